// Round 1
// baseline (10934.454 us; speedup 1.0000x reference)
//
#include <hip/hip_runtime.h>
#include <math.h>

// Pipeline (all fp32):
//   feat chain x2:  conv3x3 s2 SAME + relu  (256->128->64->32->16 spatial)
//   l2 normalize over 512 ch
//   corr = batched GEMM fA(256x512) @ fB^T          -> (B,256,256)
//   conv_r1 7x7 VALID + relu  (16,16,256)->(10,10,128)
//   conv_r2 5x5 VALID + relu  (10,10,128)->(6,6,64)
//   dense (2304->18) -> geo
//   TPS solve (12x12, shared factorization, 2 RHS) -> ax/ay per grid point
//   masked sum of corr -> out (B,)
//
// Workspace layout (floats), batch-chunked feat chain (chunk=8):
//   S1   @ 0         : 8*128*128*64  = 8,388,608
//   S2   @ 8388608   : 8*64*64*128   = 4,194,304
//   S3   @ 12582912  : 8*32*32*256   = 2,097,152
//   FA   @ 14680064  : 32*16*16*512  = 4,194,304
//   FB   @ 18874368  : 32*16*16*512  = 4,194,304   (contiguous after FA)
//   CORR @ 23068672  : 32*256*256    = 2,097,152
//   R1   @ 25165824  : 32*10*10*128  =   409,600
//   R2   @ 25575424  : 32*6*6*64     =    73,728
//   GEO  @ 25649152  : 32*18         =       576
//   AX   @ 25649728  : 32*256        =     8,192
//   AY   @ 25657920  : 32*256        =     8,192
// total ~102.7 MB

// ---------------------------------------------------------------- conv s2 SAME
// out(b,i,j,o) = relu( sum_{di,dj,c} in[b, 2i+di, 2j+dj, c] * w[di,dj,c,o] )
// pad_lo = 0, pad_hi = 1 (even input dims, k=3, s=2).
template <int CIN, int COUT, int TJ>
__global__ __launch_bounds__(COUT) void conv3s2(const float* __restrict__ in,
                                                const float* __restrict__ w,
                                                float* __restrict__ out,
                                                int Hin, int Win) {
  const int Hout = Hin >> 1, Wout = Win >> 1;
  const int o = threadIdx.x;
  const int j0 = blockIdx.x * TJ;
  const int i = blockIdx.y;
  const int b = blockIdx.z;
  const float* __restrict__ inb = in + (size_t)b * Hin * Win * CIN;
  float acc[TJ];
#pragma unroll
  for (int t = 0; t < TJ; ++t) acc[t] = 0.f;
#pragma unroll
  for (int di = 0; di < 3; ++di) {
    const int y = 2 * i + di;
    if (y < Hin) {
      const float* __restrict__ row = inb + (size_t)y * Win * CIN;
      for (int c = 0; c < CIN; ++c) {
        float xv[2 * TJ + 1];
#pragma unroll
        for (int u = 0; u < 2 * TJ + 1; ++u) {
          const int xc = 2 * j0 + u;
          xv[u] = (xc < Win) ? row[(size_t)xc * CIN + c] : 0.f;
        }
#pragma unroll
        for (int dj = 0; dj < 3; ++dj) {
          const float wv = w[(size_t)(((di * 3 + dj) * CIN) + c) * COUT + o];
#pragma unroll
          for (int t = 0; t < TJ; ++t) acc[t] += xv[2 * t + dj] * wv;
        }
      }
    }
  }
  float* __restrict__ op = out + (((size_t)b * Hout + i) * Wout + j0) * COUT + o;
#pragma unroll
  for (int t = 0; t < TJ; ++t) op[(size_t)t * COUT] = fmaxf(acc[t], 0.f);
}

// ---------------------------------------------------------------- l2 normalize
// x: (positions, 512), in-place x /= (||x|| + 1e-6). grid = positions, block 64.
__global__ __launch_bounds__(64) void l2norm_k(float* __restrict__ x) {
  const int lane = threadIdx.x;
  float* p = x + (size_t)blockIdx.x * 512;
  float v[8];
  float s = 0.f;
#pragma unroll
  for (int k = 0; k < 8; ++k) {
    v[k] = p[lane + 64 * k];
    s += v[k] * v[k];
  }
#pragma unroll
  for (int off = 32; off; off >>= 1) s += __shfl_xor(s, off, 64);
  const float inv = 1.f / (sqrtf(s) + 1e-6f);
#pragma unroll
  for (int k = 0; k < 8; ++k) p[lane + 64 * k] = v[k] * inv;
}

// ---------------------------------------------------------------- corr GEMM
// C[b][pA][pB] = sum_c fA[b][pA][c] * fB[b][pB][c].  64x64 tile, 4x4/thread.
__global__ __launch_bounds__(256) void corr_k(const float* __restrict__ fa,
                                              const float* __restrict__ fb,
                                              float* __restrict__ c) {
  __shared__ float As[32][66];
  __shared__ float Bs[32][66];
  const int b = blockIdx.z;
  const int pA0 = blockIdx.y * 64;
  const int pB0 = blockIdx.x * 64;
  const float* __restrict__ A = fa + (size_t)b * 256 * 512;
  const float* __restrict__ Bm = fb + (size_t)b * 256 * 512;
  const int t = threadIdx.x;
  const int kk = t & 31;
  const int mb = t >> 5;  // 0..7
  const int tx = t & 15, ty = t >> 4;
  float acc[4][4] = {};
  for (int k0 = 0; k0 < 512; k0 += 32) {
#pragma unroll
    for (int mm = 0; mm < 8; ++mm) {
      const int m = mm * 8 + mb;
      As[kk][m] = A[(size_t)(pA0 + m) * 512 + k0 + kk];
      Bs[kk][m] = Bm[(size_t)(pB0 + m) * 512 + k0 + kk];
    }
    __syncthreads();
#pragma unroll
    for (int k = 0; k < 32; ++k) {
      float av[4], bv[4];
#pragma unroll
      for (int u = 0; u < 4; ++u) {
        av[u] = As[k][ty * 4 + u];
        bv[u] = Bs[k][tx * 4 + u];
      }
#pragma unroll
      for (int u = 0; u < 4; ++u)
#pragma unroll
        for (int v2 = 0; v2 < 4; ++v2) acc[u][v2] += av[u] * bv[v2];
    }
    __syncthreads();
  }
#pragma unroll
  for (int u = 0; u < 4; ++u) {
    const int pA = pA0 + ty * 4 + u;
    float* __restrict__ op = c + ((size_t)b * 256 + pA) * 256 + pB0 + tx * 4;
#pragma unroll
    for (int v2 = 0; v2 < 4; ++v2) op[v2] = acc[u][v2];
  }
}

// ---------------------------------------------------------------- conv_r1
// in (B,16,16,256) [== corr], w (7,7,256,128), out (B,10,10,128) VALID + relu.
// grid (10 i, B), block (128 o, 4 c-slices), LDS reduce over slices.
__global__ __launch_bounds__(512) void convr1_k(const float* __restrict__ r,
                                                const float* __restrict__ w,
                                                float* __restrict__ out) {
  __shared__ float red[4][128][10];
  const int o = threadIdx.x;
  const int cy = threadIdx.y;
  const int i = blockIdx.x;
  const int b = blockIdx.y;
  float acc[10] = {};
  const float* __restrict__ rb = r + (size_t)b * 256 * 256;
  for (int di = 0; di < 7; ++di) {
    const float* __restrict__ rr = rb + (size_t)(i + di) * 16 * 256;
    for (int c0 = 0; c0 < 64; ++c0) {
      const int c = cy * 64 + c0;
      float xv[16];
#pragma unroll
      for (int u = 0; u < 16; ++u) xv[u] = rr[(size_t)u * 256 + c];
#pragma unroll
      for (int dj = 0; dj < 7; ++dj) {
        const float wv = w[(size_t)(((di * 7 + dj) * 256) + c) * 128 + o];
#pragma unroll
        for (int j = 0; j < 10; ++j) acc[j] += xv[j + dj] * wv;
      }
    }
  }
#pragma unroll
  for (int j = 0; j < 10; ++j) red[cy][o][j] = acc[j];
  __syncthreads();
  if (cy == 0) {
#pragma unroll
    for (int j = 0; j < 10; ++j) {
      const float s = red[0][o][j] + red[1][o][j] + red[2][o][j] + red[3][o][j];
      out[(((size_t)b * 10 + i) * 10 + j) * 128 + o] = fmaxf(s, 0.f);
    }
  }
}

// ---------------------------------------------------------------- conv_r2
// in (B,10,10,128), w (5,5,128,64), out (B,6,6,64) VALID + relu.
__global__ __launch_bounds__(256) void convr2_k(const float* __restrict__ r1,
                                                const float* __restrict__ w,
                                                float* __restrict__ out) {
  __shared__ float red[4][64][6];
  const int o = threadIdx.x;
  const int cy = threadIdx.y;
  const int i = blockIdx.x;
  const int b = blockIdx.y;
  float acc[6] = {};
  const float* __restrict__ rb = r1 + (size_t)b * 100 * 128;
  for (int di = 0; di < 5; ++di) {
    const float* __restrict__ rr = rb + (size_t)(i + di) * 10 * 128;
    for (int c0 = 0; c0 < 32; ++c0) {
      const int c = cy * 32 + c0;
      float xv[10];
#pragma unroll
      for (int u = 0; u < 10; ++u) xv[u] = rr[(size_t)u * 128 + c];
#pragma unroll
      for (int dj = 0; dj < 5; ++dj) {
        const float wv = w[(size_t)(((di * 5 + dj) * 128) + c) * 64 + o];
#pragma unroll
        for (int j = 0; j < 6; ++j) acc[j] += xv[j + dj] * wv;
      }
    }
  }
#pragma unroll
  for (int j = 0; j < 6; ++j) red[cy][o][j] = acc[j];
  __syncthreads();
  if (cy == 0) {
#pragma unroll
    for (int j = 0; j < 6; ++j) {
      const float s = red[0][o][j] + red[1][o][j] + red[2][o][j] + red[3][o][j];
      out[(((size_t)b * 6 + i) * 6 + j) * 64 + o] = fmaxf(s, 0.f);
    }
  }
}

// ---------------------------------------------------------------- dense
// geo[b][o] = r2[b,:] . Wd[:,o] + bd[o].  grid (18 o, B), block 64 (one wave).
__global__ __launch_bounds__(64) void dense_k(const float* __restrict__ r2,
                                              const float* __restrict__ wd,
                                              const float* __restrict__ bd,
                                              float* __restrict__ geo) {
  const int o = blockIdx.x;
  const int b = blockIdx.y;
  const int lane = threadIdx.x;
  const float* __restrict__ rb = r2 + (size_t)b * 2304;
  float s = 0.f;
  for (int k = lane; k < 2304; k += 64) s += rb[k] * wd[(size_t)k * 18 + o];
#pragma unroll
  for (int off = 32; off; off >>= 1) s += __shfl_xor(s, off, 64);
  if (lane == 0) geo[b * 18 + o] = s + bd[o];
}

// ---------------------------------------------------------------- TPS
__device__ __forceinline__ float tps_u(float r) { return r * r * logf(r + 1e-6f); }

__global__ __launch_bounds__(64) void tps_k(const float* __restrict__ geo,
                                            float* __restrict__ axb,
                                            float* __restrict__ ayb) {
  const int b = blockIdx.x;
  __shared__ float sDstX[9], sDstY[9];
  __shared__ float sWx[9], sWy[9];
  __shared__ float sAx[3], sAy[3];
  if (threadIdx.x == 0) {
    const float srcx[9] = {0.f, 0.5f, 1.f, 0.f, 0.5f, 1.f, 0.f, 5.f, 1.f};
    const float srcy[9] = {0.f, 0.f, 0.f, 0.5f, 0.5f, 0.5f, 1.f, 1.f, 1.f};
    float dx[9], dy[9];
    float M[12][14];
    for (int r = 0; r < 12; ++r)
      for (int cc = 0; cc < 14; ++cc) M[r][cc] = 0.f;
    for (int p = 0; p < 9; ++p) {
      const float mx = geo[b * 18 + 2 * p], my = geo[b * 18 + 2 * p + 1];
      dx[p] = srcx[p] + mx;
      dy[p] = srcy[p] + my;
      M[p][12] = -mx;  // delta_x
      M[p][13] = -my;  // delta_y
    }
    for (int p = 0; p < 9; ++p) {
      for (int q = 0; q < 9; ++q) {
        const float ddx = dx[p] - dx[q], ddy = dy[p] - dy[q];
        const float r = sqrtf(ddx * ddx + ddy * ddy + 1e-12f);
        M[p][q] = tps_u(r);
      }
      M[p][9] = 1.f;  M[p][10] = dx[p]; M[p][11] = dy[p];
      M[9][p] = 1.f;  M[10][p] = dx[p]; M[11][p] = dy[p];
    }
    // Gaussian elimination w/ partial pivoting, 2 RHS (cols 12,13)
    for (int k = 0; k < 12; ++k) {
      int piv = k;
      float best = fabsf(M[k][k]);
      for (int r = k + 1; r < 12; ++r) {
        const float v = fabsf(M[r][k]);
        if (v > best) { best = v; piv = r; }
      }
      if (piv != k)
        for (int cc = k; cc < 14; ++cc) {
          const float tmp = M[k][cc]; M[k][cc] = M[piv][cc]; M[piv][cc] = tmp;
        }
      const float d = M[k][k];
      for (int r = k + 1; r < 12; ++r) {
        const float f = M[r][k] / d;
        for (int cc = k; cc < 14; ++cc) M[r][cc] -= f * M[k][cc];
      }
    }
    float thx[12], thy[12];
    for (int k = 11; k >= 0; --k) {
      float sx = M[k][12], sy = M[k][13];
      for (int cc = k + 1; cc < 12; ++cc) {
        sx -= M[k][cc] * thx[cc];
        sy -= M[k][cc] * thy[cc];
      }
      thx[k] = sx / M[k][k];
      thy[k] = sy / M[k][k];
    }
    // reference drops theta[0] and rebuilds w0 = -(w1+..+w8)
    float swx = 0.f, swy = 0.f;
    for (int p = 1; p < 9; ++p) {
      sWx[p] = thx[p]; sWy[p] = thy[p];
      swx += thx[p];   swy += thy[p];
    }
    sWx[0] = -swx; sWy[0] = -swy;
    for (int p = 0; p < 3; ++p) { sAx[p] = thx[9 + p]; sAy[p] = thy[9 + p]; }
    for (int p = 0; p < 9; ++p) { sDstX[p] = dx[p]; sDstY[p] = dy[p]; }
  }
  __syncthreads();
  for (int p = threadIdx.x; p < 256; p += 64) {
    const int pi = p >> 4, pj = p & 15;
    const float x = pj * (1.f / 15.f), y = pi * (1.f / 15.f);
    float zx = sAx[0] + x * sAx[1] + y * sAx[2];
    float zy = sAy[0] + x * sAy[1] + y * sAy[2];
#pragma unroll
    for (int c = 0; c < 9; ++c) {
      const float ddx = x - sDstX[c], ddy = y - sDstY[c];
      const float r = sqrtf(ddx * ddx + ddy * ddy + 1e-12f);
      const float u = tps_u(r);
      zx += u * sWx[c];
      zy += u * sWy[c];
    }
    axb[b * 256 + p] = (x + zx) * 15.f;
    ayb[b * 256 + p] = (y + zy) * 15.f;
  }
}

// ---------------------------------------------------------------- masked sum
// out[b] = sum over (k,l): rows i with |i-ay|<=1, cols j with |j-ax|<=1 of
//          corr[b][i*16+j][pB],  pB = k*16+l.
__global__ __launch_bounds__(256) void masksum_k(const float* __restrict__ corr,
                                                 const float* __restrict__ axb,
                                                 const float* __restrict__ ayb,
                                                 float* __restrict__ out) {
  const int b = blockIdx.x;
  const int pB = threadIdx.x;
  const float ax = axb[b * 256 + pB];
  const float ay = ayb[b * 256 + pB];
  const float* __restrict__ cb = corr + (size_t)b * 65536;
  float s = 0.f;
  for (int i = 0; i < 16; ++i) {
    if (fabsf((float)i - ay) <= 1.0f) {
      const float* __restrict__ ci = cb + (size_t)i * 16 * 256 + pB;
      for (int j = 0; j < 16; ++j) {
        if (fabsf((float)j - ax) <= 1.0f) s += ci[(size_t)j * 256];
      }
    }
  }
  __shared__ float sm[256];
  sm[pB] = s;
  __syncthreads();
  for (int off = 128; off; off >>= 1) {
    if (pB < off) sm[pB] += sm[pB + off];
    __syncthreads();
  }
  if (pB == 0) out[b] = sm[0];
}

// ---------------------------------------------------------------- launch
extern "C" void kernel_launch(void* const* d_in, const int* in_sizes, int n_in,
                              void* d_out, int out_size, void* d_ws, size_t ws_size,
                              hipStream_t stream) {
  const float* imgA = (const float*)d_in[0];
  const float* imgB = (const float*)d_in[1];
  const float* W1 = (const float*)d_in[2];
  const float* W2 = (const float*)d_in[3];
  const float* W3 = (const float*)d_in[4];
  const float* W4 = (const float*)d_in[5];
  const float* Wr1 = (const float*)d_in[6];
  const float* Wr2 = (const float*)d_in[7];
  const float* Wd = (const float*)d_in[8];
  const float* bd = (const float*)d_in[9];

  float* ws = (float*)d_ws;
  float* S1 = ws;
  float* S2 = ws + 8388608;
  float* S3 = ws + 12582912;
  float* FAb = ws + 14680064;
  float* FBb = ws + 18874368;
  float* CORRb = ws + 23068672;
  float* R1b = ws + 25165824;
  float* R2b = ws + 25575424;
  float* GEOb = ws + 25649152;
  float* AXb = ws + 25649728;
  float* AYb = ws + 25657920;

  for (int img = 0; img < 2; ++img) {
    const float* src = img ? imgB : imgA;
    float* feat = img ? FBb : FAb;
    for (int ci = 0; ci < 4; ++ci) {
      const float* in0 = src + (size_t)ci * 8 * 256 * 256 * 3;
      conv3s2<3, 64, 4><<<dim3(32, 128, 8), 64, 0, stream>>>(in0, W1, S1, 256, 256);
      conv3s2<64, 128, 8><<<dim3(8, 64, 8), 128, 0, stream>>>(S1, W2, S2, 128, 128);
      conv3s2<128, 256, 8><<<dim3(4, 32, 8), 256, 0, stream>>>(S2, W3, S3, 64, 64);
      conv3s2<256, 512, 8><<<dim3(2, 16, 8), 512, 0, stream>>>(
          S3, W4, feat + (size_t)ci * 8 * 16 * 16 * 512, 32, 32);
    }
  }
  l2norm_k<<<16384, 64, 0, stream>>>(FAb);  // FA and FB are contiguous
  corr_k<<<dim3(4, 4, 32), 256, 0, stream>>>(FAb, FBb, CORRb);
  convr1_k<<<dim3(10, 32), dim3(128, 4), 0, stream>>>(CORRb, Wr1, R1b);
  convr2_k<<<dim3(6, 32), dim3(64, 4), 0, stream>>>(R1b, Wr2, R2b);
  dense_k<<<dim3(18, 32), 64, 0, stream>>>(R2b, Wd, bd, GEOb);
  tps_k<<<32, 64, 0, stream>>>(GEOb, AXb, AYb);
  masksum_k<<<32, 256, 0, stream>>>(CORRb, AXb, AYb, (float*)d_out);
}

// Round 3
// 2226.887 us; speedup vs baseline: 4.9102x; 4.9102x over previous
//
#include <hip/hip_runtime.h>
#include <hip/hip_bf16.h>
#include <math.h>

// ---------------------------------------------------------------------------
// Split-bf16 (hi+lo, 3xMFMA) pipeline: every MFMA GEMM uses A,B stored as
// two bf16 planes (hi = bf16(x), lo = bf16(x-hi)); product = ah*bh + ah*bl +
// al*bh accumulated in fp32 -> ~2^-16 relative error, near-fp32 accuracy.
// This kills the mask-flip error amplifier (round-1 absmax 32 -> ~3).
//
//   conv1 (CIN=3)      : fp32 vector kernel, emits hi/lo bf16
//   conv2/3/4          : implicit-GEMM split-bf16 MFMA + relu, hi/lo out
//   l2norm             : reconstruct hi+lo, fp32 norm, re-split
//   corr               : batched split MFMA, fp32 out (masksum) + hi/lo out
//   conv_r1, conv_r2   : split MFMA, split-K fp32 partials + sum/relu
//   dense/tps/masksum  : fp32
//
// Workspace (float units; bf16 pair planes stored as hi then lo):
//   WT2h  @ 0         73728     (pair of 576x128)
//   WT3h  @ 73728     294912
//   WT4h  @ 368640    1179648
//   WTr1h @ 1548288   1605632
//   WTr2h @ 3153920   204800
//   FEATh @ 3358720   8388608   (pair of 2*32*256*512)
//   S1h   @ 11747328  8388608   (pair of 8*128*128*64, per-chunk)
//   S2h   @ 20135936  4194304   (pair of 8*64*64*128, per-chunk)
//   S3h   @ 24330240  2097152   (pair of 8*32*32*256, per-chunk) -> 105.7 MB
//   -- after feature chain, CORR region overlaps S1h:
//   CORRf @ 11747328  2097152   (fp32)
//   CORRh @ 13844480  2097152   (pair)
//   R1p   @ 15941632  1638400   (4 x 409600 fp32)
//   R1h   @ 17580032  409600    (pair of 32*10*10*128)
//   R2p   @ 17989632  368640    (5 x 73728 fp32)
//   R2f   @ 18358272  73728
//   GEO   @ 18432000, AX @ 18432576, AY @ 18440768
// ---------------------------------------------------------------------------

typedef __attribute__((ext_vector_type(8))) short bf16x8;
typedef __attribute__((ext_vector_type(4))) float f32x4;

__device__ __forceinline__ unsigned short f2bf(float f) {
  __hip_bfloat16 h = __float2bfloat16(f);
  return __builtin_bit_cast(unsigned short, h);
}
__device__ __forceinline__ float bf2f(unsigned short u) {
  return __uint_as_float(((unsigned int)u) << 16);
}

// ---------------------------------------------------------------- weight prep
// w (K, COUT) fp32 -> wt hi plane [o][k], lo plane at +K*C.
__global__ __launch_bounds__(256) void wt_k(const float* __restrict__ w,
                                            unsigned short* __restrict__ wt,
                                            int K, int C) {
  const int idx = blockIdx.x * 256 + threadIdx.x;
  if (idx < K * C) {
    const int k = idx / C, o = idx % C;
    const float v = w[idx];
    const unsigned short hi = f2bf(v);
    wt[(size_t)o * K + k] = hi;
    wt[(size_t)K * C + (size_t)o * K + k] = f2bf(v - bf2f(hi));
  }
}

// ---------------------------------------------------------------- conv1
// (8,256,256,3) fp32 -> (8,128,128,64) hi/lo bf16, stride2 SAME + relu.
__global__ __launch_bounds__(64) void conv1_k(const float* __restrict__ in,
                                              const float* __restrict__ w,
                                              unsigned short* __restrict__ out,
                                              int oLo) {
  const int o = threadIdx.x;
  const int j0 = blockIdx.x * 4;
  const int i = blockIdx.y;
  const int b = blockIdx.z;
  const float* __restrict__ inb = in + (size_t)b * 256 * 256 * 3;
  float acc[4] = {0.f, 0.f, 0.f, 0.f};
  const bool full = (2 * j0 + 8) < 256;
#pragma unroll
  for (int di = 0; di < 3; ++di) {
    const int y = 2 * i + di;
    if (y < 256) {
      const float* __restrict__ row = inb + ((size_t)y * 256 + 2 * j0) * 3;
      float xf[28];
      if (full) {
#pragma unroll
        for (int q = 0; q < 14; ++q) {
          const float2 v = ((const float2*)row)[q];
          xf[2 * q] = v.x; xf[2 * q + 1] = v.y;
        }
      } else {
#pragma unroll
        for (int q = 0; q < 12; ++q) {
          const float2 v = ((const float2*)row)[q];
          xf[2 * q] = v.x; xf[2 * q + 1] = v.y;
        }
        xf[24] = xf[25] = xf[26] = xf[27] = 0.f;
      }
#pragma unroll
      for (int c = 0; c < 3; ++c)
#pragma unroll
        for (int dj = 0; dj < 3; ++dj) {
          const float wv = w[(size_t)(((di * 3 + dj) * 3) + c) * 64 + o];
#pragma unroll
          for (int t = 0; t < 4; ++t) acc[t] += xf[(2 * t + dj) * 3 + c] * wv;
        }
    }
  }
#pragma unroll
  for (int t = 0; t < 4; ++t) {
    const size_t idx = (((size_t)b * 128 + i) * 128 + j0 + t) * 64 + o;
    const float v = fmaxf(acc[t], 0.f);
    const unsigned short hi = f2bf(v);
    out[idx] = hi;
    out[(size_t)oLo + idx] = f2bf(v - bf2f(hi));
  }
}

// ---------------------------------------------------------------- MFMA conv
// Implicit GEMM, split-bf16: out[m][n] = sum_k A[m][k]*Wt[n][k],
// A/B each as hi plane + lo plane (offsets aLo/bLo in elements).
template <int MT, int NT, int CIN, int COUT, int KH, int KW, int STRIDE,
          int SAMEPAD, int SPLITK, int RELU, int BATB, int OUTF32, int SK>
__global__ __launch_bounds__(256) void gemm_conv(
    const unsigned short* __restrict__ in, const unsigned short* __restrict__ wt,
    unsigned short* __restrict__ outh, float* __restrict__ outf,
    int Hin, int Win, int Hout, int Wout, int aLo, int bLo, int oLo) {
  const int KTOT = KH * KW * CIN;
  const int lane = threadIdx.x & 63;
  const int wid = threadIdx.x >> 6;
  const int lrow = lane & 15;
  const int quad = lane >> 4;
  const int m0 = (blockIdx.x * 4 + wid) * (16 * MT);
  const int n0 = blockIdx.y * (16 * NT);

  int pix[MT], i2a[MT], j2a[MT];
#pragma unroll
  for (int mi = 0; mi < MT; ++mi) {
    const int m = m0 + mi * 16 + lrow;
    const int j = m % Wout;
    const int t = m / Wout;
    const int i = t % Hout;
    const int b = t / Hout;
    i2a[mi] = STRIDE * i;
    j2a[mi] = STRIDE * j;
    pix[mi] = (b * Hin + i2a[mi]) * Win + j2a[mi];
  }
  const unsigned short* wb = wt;
  if (BATB) wb += (size_t)(m0 / (Hout * Wout)) * COUT * KTOT;
  const unsigned short* brow[NT];
#pragma unroll
  for (int ni = 0; ni < NT; ++ni)
    brow[ni] = wb + (size_t)(n0 + ni * 16 + lrow) * KTOT + quad * 8;

  const f32x4 zf = {0.f, 0.f, 0.f, 0.f};
  const bf16x8 zb = {0, 0, 0, 0, 0, 0, 0, 0};
  f32x4 acc[MT][NT];
#pragma unroll
  for (int mi = 0; mi < MT; ++mi)
#pragma unroll
    for (int ni = 0; ni < NT; ++ni) acc[mi][ni] = zf;

  int tap_lo = 0, tap_hi = KH * KW;
  if (SPLITK) {
    tap_lo = (int)blockIdx.z * KH * KW / SK;
    tap_hi = ((int)blockIdx.z + 1) * KH * KW / SK;
  }
  for (int tap = tap_lo; tap < tap_hi; ++tap) {
    const int di = tap / KW, dj = tap % KW;
    const unsigned short* ap[MT];
    bool av[MT];
#pragma unroll
    for (int mi = 0; mi < MT; ++mi) {
      av[mi] = !SAMEPAD || ((i2a[mi] + di < Hin) && (j2a[mi] + dj < Win));
      ap[mi] = in + ((size_t)pix[mi] + di * Win + dj) * CIN + quad * 8;
    }
    const int ko = tap * CIN;
#pragma unroll
    for (int c0 = 0; c0 < CIN; c0 += 32) {
      bf16x8 ah[MT], al[MT], bh[NT], bl[NT];
#pragma unroll
      for (int mi = 0; mi < MT; ++mi) {
        ah[mi] = av[mi] ? *(const bf16x8*)(ap[mi] + c0) : zb;
        al[mi] = av[mi] ? *(const bf16x8*)(ap[mi] + aLo + c0) : zb;
      }
#pragma unroll
      for (int ni = 0; ni < NT; ++ni) {
        bh[ni] = *(const bf16x8*)(brow[ni] + ko + c0);
        bl[ni] = *(const bf16x8*)(brow[ni] + bLo + ko + c0);
      }
#pragma unroll
      for (int mi = 0; mi < MT; ++mi)
#pragma unroll
        for (int ni = 0; ni < NT; ++ni) {
          acc[mi][ni] = __builtin_amdgcn_mfma_f32_16x16x32_bf16(ah[mi], bl[ni],
                                                                acc[mi][ni], 0, 0, 0);
          acc[mi][ni] = __builtin_amdgcn_mfma_f32_16x16x32_bf16(al[mi], bh[ni],
                                                                acc[mi][ni], 0, 0, 0);
          acc[mi][ni] = __builtin_amdgcn_mfma_f32_16x16x32_bf16(ah[mi], bh[ni],
                                                                acc[mi][ni], 0, 0, 0);
        }
    }
  }
  const size_t slice = SPLITK ? (size_t)blockIdx.z * ((size_t)gridDim.x * 64 * MT * COUT) : 0;
#pragma unroll
  for (int mi = 0; mi < MT; ++mi)
#pragma unroll
    for (int ni = 0; ni < NT; ++ni)
#pragma unroll
      for (int r = 0; r < 4; ++r) {
        const int row = m0 + mi * 16 + quad * 4 + r;
        const int col = n0 + ni * 16 + lrow;
        const size_t idx = (size_t)row * COUT + col;
        float v = acc[mi][ni][r];
        if (SPLITK) {
          outf[slice + idx] = v;
        } else if (OUTF32) {
          outf[idx] = v;
          const unsigned short hi = f2bf(v);
          outh[idx] = hi;
          outh[(size_t)oLo + idx] = f2bf(v - bf2f(hi));
        } else {
          if (RELU) v = fmaxf(v, 0.f);
          const unsigned short hi = f2bf(v);
          outh[idx] = hi;
          outh[(size_t)oLo + idx] = f2bf(v - bf2f(hi));
        }
      }
}

// ---------------------------------------------------------------- split-K epi
__global__ __launch_bounds__(256) void sum_relu_h(const float* __restrict__ p,
                                                  unsigned short* __restrict__ o,
                                                  int n, int parts, int oLo) {
  const int idx = blockIdx.x * 256 + threadIdx.x;
  if (idx < n) {
    float v = 0.f;
    for (int s = 0; s < parts; ++s) v += p[(size_t)s * n + idx];
    v = fmaxf(v, 0.f);
    const unsigned short hi = f2bf(v);
    o[idx] = hi;
    o[(size_t)oLo + idx] = f2bf(v - bf2f(hi));
  }
}
__global__ __launch_bounds__(256) void sum_relu_f(const float* __restrict__ p,
                                                  float* __restrict__ o,
                                                  int n, int parts) {
  const int idx = blockIdx.x * 256 + threadIdx.x;
  if (idx < n) {
    float v = 0.f;
    for (int s = 0; s < parts; ++s) v += p[(size_t)s * n + idx];
    o[idx] = fmaxf(v, 0.f);
  }
}

// ---------------------------------------------------------------- l2 normalize
// hi/lo planes, one wave per position (512 ch).
__global__ __launch_bounds__(64) void l2norm_h(unsigned short* __restrict__ x,
                                               int loOff) {
  const int lane = threadIdx.x;
  unsigned short* ph = x + (size_t)blockIdx.x * 512 + lane * 8;
  unsigned short* pl = ph + (size_t)loOff;
  bf16x8 vh = *(bf16x8*)ph;
  bf16x8 vl = *(bf16x8*)pl;
  float f[8];
  float s = 0.f;
#pragma unroll
  for (int k = 0; k < 8; ++k) {
    f[k] = bf2f((unsigned short)vh[k]) + bf2f((unsigned short)vl[k]);
    s += f[k] * f[k];
  }
#pragma unroll
  for (int off = 32; off; off >>= 1) s += __shfl_xor(s, off, 64);
  const float inv = 1.f / (sqrtf(s) + 1e-6f);
#pragma unroll
  for (int k = 0; k < 8; ++k) {
    const float v = f[k] * inv;
    const unsigned short hi = f2bf(v);
    vh[k] = (short)hi;
    vl[k] = (short)f2bf(v - bf2f(hi));
  }
  *(bf16x8*)ph = vh;
  *(bf16x8*)pl = vl;
}

// ---------------------------------------------------------------- dense
__global__ __launch_bounds__(64) void dense_k(const float* __restrict__ r2,
                                              const float* __restrict__ wd,
                                              const float* __restrict__ bd,
                                              float* __restrict__ geo) {
  const int o = blockIdx.x;
  const int b = blockIdx.y;
  const int lane = threadIdx.x;
  const float* __restrict__ rb = r2 + (size_t)b * 2304;
  float s = 0.f;
  for (int k = lane; k < 2304; k += 64) s += rb[k] * wd[(size_t)k * 18 + o];
#pragma unroll
  for (int off = 32; off; off >>= 1) s += __shfl_xor(s, off, 64);
  if (lane == 0) geo[b * 18 + o] = s + bd[o];
}

// ---------------------------------------------------------------- TPS
__device__ __forceinline__ float tps_u(float r) { return r * r * logf(r + 1e-6f); }

__global__ __launch_bounds__(64) void tps_k(const float* __restrict__ geo,
                                            float* __restrict__ axb,
                                            float* __restrict__ ayb) {
  const int b = blockIdx.x;
  __shared__ float sDstX[9], sDstY[9];
  __shared__ float sWx[9], sWy[9];
  __shared__ float sAx[3], sAy[3];
  if (threadIdx.x == 0) {
    const float srcx[9] = {0.f, 0.5f, 1.f, 0.f, 0.5f, 1.f, 0.f, 5.f, 1.f};
    const float srcy[9] = {0.f, 0.f, 0.f, 0.5f, 0.5f, 0.5f, 1.f, 1.f, 1.f};
    float dx[9], dy[9];
    float M[12][14];
    for (int r = 0; r < 12; ++r)
      for (int cc = 0; cc < 14; ++cc) M[r][cc] = 0.f;
    for (int p = 0; p < 9; ++p) {
      const float mx = geo[b * 18 + 2 * p], my = geo[b * 18 + 2 * p + 1];
      dx[p] = srcx[p] + mx;
      dy[p] = srcy[p] + my;
      M[p][12] = -mx;
      M[p][13] = -my;
    }
    for (int p = 0; p < 9; ++p) {
      for (int q = 0; q < 9; ++q) {
        const float ddx = dx[p] - dx[q], ddy = dy[p] - dy[q];
        const float r = sqrtf(ddx * ddx + ddy * ddy + 1e-12f);
        M[p][q] = tps_u(r);
      }
      M[p][9] = 1.f;  M[p][10] = dx[p]; M[p][11] = dy[p];
      M[9][p] = 1.f;  M[10][p] = dx[p]; M[11][p] = dy[p];
    }
    for (int k = 0; k < 12; ++k) {
      int piv = k;
      float best = fabsf(M[k][k]);
      for (int r = k + 1; r < 12; ++r) {
        const float v = fabsf(M[r][k]);
        if (v > best) { best = v; piv = r; }
      }
      if (piv != k)
        for (int cc = k; cc < 14; ++cc) {
          const float tmp = M[k][cc]; M[k][cc] = M[piv][cc]; M[piv][cc] = tmp;
        }
      const float d = M[k][k];
      for (int r = k + 1; r < 12; ++r) {
        const float f = M[r][k] / d;
        for (int cc = k; cc < 14; ++cc) M[r][cc] -= f * M[k][cc];
      }
    }
    float thx[12], thy[12];
    for (int k = 11; k >= 0; --k) {
      float sx = M[k][12], sy = M[k][13];
      for (int cc = k + 1; cc < 12; ++cc) {
        sx -= M[k][cc] * thx[cc];
        sy -= M[k][cc] * thy[cc];
      }
      thx[k] = sx / M[k][k];
      thy[k] = sy / M[k][k];
    }
    float swx = 0.f, swy = 0.f;
    for (int p = 1; p < 9; ++p) {
      sWx[p] = thx[p]; sWy[p] = thy[p];
      swx += thx[p];   swy += thy[p];
    }
    sWx[0] = -swx; sWy[0] = -swy;
    for (int p = 0; p < 3; ++p) { sAx[p] = thx[9 + p]; sAy[p] = thy[9 + p]; }
    for (int p = 0; p < 9; ++p) { sDstX[p] = dx[p]; sDstY[p] = dy[p]; }
  }
  __syncthreads();
  for (int p = threadIdx.x; p < 256; p += 64) {
    const int pi = p >> 4, pj = p & 15;
    const float x = pj * (1.f / 15.f), y = pi * (1.f / 15.f);
    float zx = sAx[0] + x * sAx[1] + y * sAx[2];
    float zy = sAy[0] + x * sAy[1] + y * sAy[2];
#pragma unroll
    for (int c = 0; c < 9; ++c) {
      const float ddx = x - sDstX[c], ddy = y - sDstY[c];
      const float r = sqrtf(ddx * ddx + ddy * ddy + 1e-12f);
      const float u = tps_u(r);
      zx += u * sWx[c];
      zy += u * sWy[c];
    }
    axb[b * 256 + p] = (x + zx) * 15.f;
    ayb[b * 256 + p] = (y + zy) * 15.f;
  }
}

// ---------------------------------------------------------------- masked sum
__global__ __launch_bounds__(256) void masksum_k(const float* __restrict__ corr,
                                                 const float* __restrict__ axb,
                                                 const float* __restrict__ ayb,
                                                 float* __restrict__ out) {
  const int b = blockIdx.x;
  const int pB = threadIdx.x;
  const float ax = axb[b * 256 + pB];
  const float ay = ayb[b * 256 + pB];
  const float* __restrict__ cb = corr + (size_t)b * 65536;
  float s = 0.f;
  for (int i = 0; i < 16; ++i) {
    if (fabsf((float)i - ay) <= 1.0f) {
      const float* __restrict__ ci = cb + (size_t)i * 16 * 256 + pB;
      for (int j = 0; j < 16; ++j) {
        if (fabsf((float)j - ax) <= 1.0f) s += ci[(size_t)j * 256];
      }
    }
  }
  __shared__ float sm[256];
  sm[pB] = s;
  __syncthreads();
  for (int off = 128; off; off >>= 1) {
    if (pB < off) sm[pB] += sm[pB + off];
    __syncthreads();
  }
  if (pB == 0) out[b] = sm[0];
}

// ---------------------------------------------------------------- launch
extern "C" void kernel_launch(void* const* d_in, const int* in_sizes, int n_in,
                              void* d_out, int out_size, void* d_ws, size_t ws_size,
                              hipStream_t stream) {
  const float* imgA = (const float*)d_in[0];
  const float* imgB = (const float*)d_in[1];
  const float* W1 = (const float*)d_in[2];
  const float* W2 = (const float*)d_in[3];
  const float* W3 = (const float*)d_in[4];
  const float* W4 = (const float*)d_in[5];
  const float* Wr1 = (const float*)d_in[6];
  const float* Wr2 = (const float*)d_in[7];
  const float* Wd = (const float*)d_in[8];
  const float* bd = (const float*)d_in[9];

  float* ws = (float*)d_ws;
  unsigned short* WT2h = (unsigned short*)(ws + 0);
  unsigned short* WT3h = (unsigned short*)(ws + 73728);
  unsigned short* WT4h = (unsigned short*)(ws + 368640);
  unsigned short* WTr1h = (unsigned short*)(ws + 1548288);
  unsigned short* WTr2h = (unsigned short*)(ws + 3153920);
  unsigned short* FEATh = (unsigned short*)(ws + 3358720);
  unsigned short* S1h = (unsigned short*)(ws + 11747328);
  unsigned short* S2h = (unsigned short*)(ws + 20135936);
  unsigned short* S3h = (unsigned short*)(ws + 24330240);
  float* CORRf = ws + 11747328;   // overlaps S1h (feature chain finished)
  unsigned short* CORRh = (unsigned short*)(ws + 13844480);
  float* R1p = ws + 15941632;
  unsigned short* R1h = (unsigned short*)(ws + 17580032);
  float* R2p = ws + 17989632;
  float* R2f = ws + 18358272;
  float* GEOb = ws + 18432000;
  float* AXb = ws + 18432576;
  float* AYb = ws + 18440768;

  // weight split+transpose
  wt_k<<<288, 256, 0, stream>>>(W2, WT2h, 576, 128);
  wt_k<<<1152, 256, 0, stream>>>(W3, WT3h, 1152, 256);
  wt_k<<<4608, 256, 0, stream>>>(W4, WT4h, 2304, 512);
  wt_k<<<6272, 256, 0, stream>>>(Wr1, WTr1h, 12544, 128);
  wt_k<<<800, 256, 0, stream>>>(Wr2, WTr2h, 3200, 64);

  for (int img = 0; img < 2; ++img) {
    const float* src = img ? imgB : imgA;
    for (int ci = 0; ci < 4; ++ci) {
      conv1_k<<<dim3(32, 128, 8), 64, 0, stream>>>(src + (size_t)ci * 1572864, W1,
                                                   S1h, 8388608);
      gemm_conv<4, 4, 64, 128, 3, 3, 2, 1, 0, 1, 0, 0, 1>
          <<<dim3(128, 2, 1), 256, 0, stream>>>(S1h, WT2h, S2h, nullptr,
                                                128, 128, 64, 64,
                                                8388608, 73728, 4194304);
      gemm_conv<4, 4, 128, 256, 3, 3, 2, 1, 0, 1, 0, 0, 1>
          <<<dim3(32, 4, 1), 256, 0, stream>>>(S2h, WT3h, S3h, nullptr,
                                               64, 64, 32, 32,
                                               4194304, 294912, 2097152);
      gemm_conv<2, 4, 256, 512, 3, 3, 2, 1, 0, 1, 0, 0, 1>
          <<<dim3(16, 8, 1), 256, 0, stream>>>(
              S3h, WT4h, FEATh + (size_t)img * 4194304 + (size_t)ci * 1048576,
              nullptr, 32, 32, 16, 16, 2097152, 1179648, 8388608);
    }
  }
  l2norm_h<<<16384, 64, 0, stream>>>(FEATh, 8388608);
  // corr: A = FA, B = FB rows (batched), fp32 + hi/lo out
  gemm_conv<2, 4, 512, 256, 1, 1, 1, 0, 0, 0, 1, 1, 1>
      <<<dim3(64, 4, 1), 256, 0, stream>>>(FEATh, FEATh + 4194304, CORRh, CORRf,
                                           16, 16, 16, 16,
                                           8388608, 8388608, 2097152);
  // conv_r1 split-K over 49 taps
  gemm_conv<2, 4, 256, 128, 7, 7, 1, 0, 1, 0, 0, 0, 4>
      <<<dim3(25, 2, 4), 256, 0, stream>>>(CORRh, WTr1h, nullptr, R1p,
                                           16, 16, 10, 10,
                                           2097152, 1605632, 0);
  sum_relu_h<<<1600, 256, 0, stream>>>(R1p, R1h, 409600, 4, 409600);
  // conv_r2 split-K over 25 taps
  gemm_conv<1, 4, 128, 64, 5, 5, 1, 0, 1, 0, 0, 0, 5>
      <<<dim3(18, 1, 5), 256, 0, stream>>>(R1h, WTr2h, nullptr, R2p,
                                           10, 10, 6, 6,
                                           409600, 204800, 0);
  sum_relu_f<<<288, 256, 0, stream>>>(R2p, R2f, 73728, 5);
  dense_k<<<dim3(18, 32), 64, 0, stream>>>(R2f, Wd, bd, GEOb);
  tps_k<<<32, 64, 0, stream>>>(GEOb, AXb, AYb);
  masksum_k<<<32, 256, 0, stream>>>(CORRf, AXb, AYb, (float*)d_out);
}

// Round 4
// 1699.731 us; speedup vs baseline: 6.4331x; 1.3101x over previous
//
#include <hip/hip_runtime.h>
#include <hip/hip_bf16.h>
#include <math.h>

// ---------------------------------------------------------------------------
// Split-bf16 (hi+lo, 3xMFMA) pipeline, round 4: occupancy fixes.
//   - conv_r1 split-K 4->7, conv_r2 5->25 (sub-1-wave/SIMD -> 1.4-1.8/SIMD)
//   - conv3/conv4 de-chunked (per-image full batch, 512-block grids) when
//     ws_size permits (147.7 MB layout); fallback to chunked layout otherwise
//   - conv2 MT 4->2, corr MT 2->1 (2x blocks)
//
// Primary workspace layout (float units):
//   WT2h @0 (73728)  WT3h @73728 (294912)  WT4h @368640 (1179648)
//   WTr1h @1548288 (1605632)  WTr2h @3153920 (204800)
//   FEATh @3358720 (8388608)   pair, plane = 8388608 el (2 img x 32 x 256 x 512)
//   S1h  @11747328 (8388608)   pair, chunk of 8 batches   [S3h overlays after]
//   S3h  @11747328 (8388608)   pair, per-image 32 batches
//   S2h  @20135936 (16777216)  pair, per-image 32 batches -> peak 36913152 fl
//   CORR overlay @20135936 (S2 dead): CORRf(2097152) CORRh(2097152)
//     R1p(7x409600) R1h(409600) R2p(25x73728) R2f GEO AX AY
// ---------------------------------------------------------------------------

typedef __attribute__((ext_vector_type(8))) short bf16x8;
typedef __attribute__((ext_vector_type(4))) float f32x4;

__device__ __forceinline__ unsigned short f2bf(float f) {
  __hip_bfloat16 h = __float2bfloat16(f);
  return __builtin_bit_cast(unsigned short, h);
}
__device__ __forceinline__ float bf2f(unsigned short u) {
  return __uint_as_float(((unsigned int)u) << 16);
}

// ---------------------------------------------------------------- weight prep
__global__ __launch_bounds__(256) void wt_k(const float* __restrict__ w,
                                            unsigned short* __restrict__ wt,
                                            int K, int C) {
  const int idx = blockIdx.x * 256 + threadIdx.x;
  if (idx < K * C) {
    const int k = idx / C, o = idx % C;
    const float v = w[idx];
    const unsigned short hi = f2bf(v);
    wt[(size_t)o * K + k] = hi;
    wt[(size_t)K * C + (size_t)o * K + k] = f2bf(v - bf2f(hi));
  }
}

// ---------------------------------------------------------------- conv1
__global__ __launch_bounds__(64) void conv1_k(const float* __restrict__ in,
                                              const float* __restrict__ w,
                                              unsigned short* __restrict__ out,
                                              int oLo) {
  const int o = threadIdx.x;
  const int j0 = blockIdx.x * 4;
  const int i = blockIdx.y;
  const int b = blockIdx.z;
  const float* __restrict__ inb = in + (size_t)b * 256 * 256 * 3;
  float acc[4] = {0.f, 0.f, 0.f, 0.f};
  const bool full = (2 * j0 + 8) < 256;
#pragma unroll
  for (int di = 0; di < 3; ++di) {
    const int y = 2 * i + di;
    if (y < 256) {
      const float* __restrict__ row = inb + ((size_t)y * 256 + 2 * j0) * 3;
      float xf[28];
      if (full) {
#pragma unroll
        for (int q = 0; q < 14; ++q) {
          const float2 v = ((const float2*)row)[q];
          xf[2 * q] = v.x; xf[2 * q + 1] = v.y;
        }
      } else {
#pragma unroll
        for (int q = 0; q < 12; ++q) {
          const float2 v = ((const float2*)row)[q];
          xf[2 * q] = v.x; xf[2 * q + 1] = v.y;
        }
        xf[24] = xf[25] = xf[26] = xf[27] = 0.f;
      }
#pragma unroll
      for (int c = 0; c < 3; ++c)
#pragma unroll
        for (int dj = 0; dj < 3; ++dj) {
          const float wv = w[(size_t)(((di * 3 + dj) * 3) + c) * 64 + o];
#pragma unroll
          for (int t = 0; t < 4; ++t) acc[t] += xf[(2 * t + dj) * 3 + c] * wv;
        }
    }
  }
#pragma unroll
  for (int t = 0; t < 4; ++t) {
    const size_t idx = (((size_t)b * 128 + i) * 128 + j0 + t) * 64 + o;
    const float v = fmaxf(acc[t], 0.f);
    const unsigned short hi = f2bf(v);
    out[idx] = hi;
    out[(size_t)oLo + idx] = f2bf(v - bf2f(hi));
  }
}

// ---------------------------------------------------------------- MFMA conv
template <int MT, int NT, int CIN, int COUT, int KH, int KW, int STRIDE,
          int SAMEPAD, int SPLITK, int RELU, int BATB, int OUTF32, int SK>
__global__ __launch_bounds__(256) void gemm_conv(
    const unsigned short* __restrict__ in, const unsigned short* __restrict__ wt,
    unsigned short* __restrict__ outh, float* __restrict__ outf,
    int Hin, int Win, int Hout, int Wout, int aLo, int bLo, int oLo) {
  const int KTOT = KH * KW * CIN;
  const int lane = threadIdx.x & 63;
  const int wid = threadIdx.x >> 6;
  const int lrow = lane & 15;
  const int quad = lane >> 4;
  const int m0 = (blockIdx.x * 4 + wid) * (16 * MT);
  const int n0 = blockIdx.y * (16 * NT);

  int pix[MT], i2a[MT], j2a[MT];
#pragma unroll
  for (int mi = 0; mi < MT; ++mi) {
    const int m = m0 + mi * 16 + lrow;
    const int j = m % Wout;
    const int t = m / Wout;
    const int i = t % Hout;
    const int b = t / Hout;
    i2a[mi] = STRIDE * i;
    j2a[mi] = STRIDE * j;
    pix[mi] = (b * Hin + i2a[mi]) * Win + j2a[mi];
  }
  const unsigned short* wb = wt;
  if (BATB) wb += (size_t)(m0 / (Hout * Wout)) * COUT * KTOT;
  const unsigned short* brow[NT];
#pragma unroll
  for (int ni = 0; ni < NT; ++ni)
    brow[ni] = wb + (size_t)(n0 + ni * 16 + lrow) * KTOT + quad * 8;

  const f32x4 zf = {0.f, 0.f, 0.f, 0.f};
  const bf16x8 zb = {0, 0, 0, 0, 0, 0, 0, 0};
  f32x4 acc[MT][NT];
#pragma unroll
  for (int mi = 0; mi < MT; ++mi)
#pragma unroll
    for (int ni = 0; ni < NT; ++ni) acc[mi][ni] = zf;

  int tap_lo = 0, tap_hi = KH * KW;
  if (SPLITK) {
    tap_lo = (int)blockIdx.z * KH * KW / SK;
    tap_hi = ((int)blockIdx.z + 1) * KH * KW / SK;
  }
  for (int tap = tap_lo; tap < tap_hi; ++tap) {
    const int di = tap / KW, dj = tap % KW;
    const unsigned short* ap[MT];
    bool av[MT];
#pragma unroll
    for (int mi = 0; mi < MT; ++mi) {
      av[mi] = !SAMEPAD || ((i2a[mi] + di < Hin) && (j2a[mi] + dj < Win));
      ap[mi] = in + ((size_t)pix[mi] + di * Win + dj) * CIN + quad * 8;
    }
    const int ko = tap * CIN;
#pragma unroll
    for (int c0 = 0; c0 < CIN; c0 += 32) {
      bf16x8 ah[MT], al[MT], bh[NT], bl[NT];
#pragma unroll
      for (int mi = 0; mi < MT; ++mi) {
        ah[mi] = av[mi] ? *(const bf16x8*)(ap[mi] + c0) : zb;
        al[mi] = av[mi] ? *(const bf16x8*)(ap[mi] + aLo + c0) : zb;
      }
#pragma unroll
      for (int ni = 0; ni < NT; ++ni) {
        bh[ni] = *(const bf16x8*)(brow[ni] + ko + c0);
        bl[ni] = *(const bf16x8*)(brow[ni] + bLo + ko + c0);
      }
#pragma unroll
      for (int mi = 0; mi < MT; ++mi)
#pragma unroll
        for (int ni = 0; ni < NT; ++ni) {
          acc[mi][ni] = __builtin_amdgcn_mfma_f32_16x16x32_bf16(ah[mi], bl[ni],
                                                                acc[mi][ni], 0, 0, 0);
          acc[mi][ni] = __builtin_amdgcn_mfma_f32_16x16x32_bf16(al[mi], bh[ni],
                                                                acc[mi][ni], 0, 0, 0);
          acc[mi][ni] = __builtin_amdgcn_mfma_f32_16x16x32_bf16(ah[mi], bh[ni],
                                                                acc[mi][ni], 0, 0, 0);
        }
    }
  }
  const size_t slice = SPLITK ? (size_t)blockIdx.z * ((size_t)gridDim.x * 64 * MT * COUT) : 0;
#pragma unroll
  for (int mi = 0; mi < MT; ++mi)
#pragma unroll
    for (int ni = 0; ni < NT; ++ni)
#pragma unroll
      for (int r = 0; r < 4; ++r) {
        const int row = m0 + mi * 16 + quad * 4 + r;
        const int col = n0 + ni * 16 + lrow;
        const size_t idx = (size_t)row * COUT + col;
        float v = acc[mi][ni][r];
        if (SPLITK) {
          outf[slice + idx] = v;
        } else if (OUTF32) {
          outf[idx] = v;
          const unsigned short hi = f2bf(v);
          outh[idx] = hi;
          outh[(size_t)oLo + idx] = f2bf(v - bf2f(hi));
        } else {
          if (RELU) v = fmaxf(v, 0.f);
          const unsigned short hi = f2bf(v);
          outh[idx] = hi;
          outh[(size_t)oLo + idx] = f2bf(v - bf2f(hi));
        }
      }
}

// ---------------------------------------------------------------- split-K epi
__global__ __launch_bounds__(256) void sum_relu_h(const float* __restrict__ p,
                                                  unsigned short* __restrict__ o,
                                                  int n, int parts, int oLo) {
  const int idx = blockIdx.x * 256 + threadIdx.x;
  if (idx < n) {
    float v = 0.f;
    for (int s = 0; s < parts; ++s) v += p[(size_t)s * n + idx];
    v = fmaxf(v, 0.f);
    const unsigned short hi = f2bf(v);
    o[idx] = hi;
    o[(size_t)oLo + idx] = f2bf(v - bf2f(hi));
  }
}
__global__ __launch_bounds__(256) void sum_relu_f(const float* __restrict__ p,
                                                  float* __restrict__ o,
                                                  int n, int parts) {
  const int idx = blockIdx.x * 256 + threadIdx.x;
  if (idx < n) {
    float v = 0.f;
    for (int s = 0; s < parts; ++s) v += p[(size_t)s * n + idx];
    o[idx] = fmaxf(v, 0.f);
  }
}

// ---------------------------------------------------------------- l2 normalize
__global__ __launch_bounds__(64) void l2norm_h(unsigned short* __restrict__ x,
                                               int loOff) {
  const int lane = threadIdx.x;
  unsigned short* ph = x + (size_t)blockIdx.x * 512 + lane * 8;
  unsigned short* pl = ph + (size_t)loOff;
  bf16x8 vh = *(bf16x8*)ph;
  bf16x8 vl = *(bf16x8*)pl;
  float f[8];
  float s = 0.f;
#pragma unroll
  for (int k = 0; k < 8; ++k) {
    f[k] = bf2f((unsigned short)vh[k]) + bf2f((unsigned short)vl[k]);
    s += f[k] * f[k];
  }
#pragma unroll
  for (int off = 32; off; off >>= 1) s += __shfl_xor(s, off, 64);
  const float inv = 1.f / (sqrtf(s) + 1e-6f);
#pragma unroll
  for (int k = 0; k < 8; ++k) {
    const float v = f[k] * inv;
    const unsigned short hi = f2bf(v);
    vh[k] = (short)hi;
    vl[k] = (short)f2bf(v - bf2f(hi));
  }
  *(bf16x8*)ph = vh;
  *(bf16x8*)pl = vl;
}

// ---------------------------------------------------------------- dense
__global__ __launch_bounds__(64) void dense_k(const float* __restrict__ r2,
                                              const float* __restrict__ wd,
                                              const float* __restrict__ bd,
                                              float* __restrict__ geo) {
  const int o = blockIdx.x;
  const int b = blockIdx.y;
  const int lane = threadIdx.x;
  const float* __restrict__ rb = r2 + (size_t)b * 2304;
  float s = 0.f;
  for (int k = lane; k < 2304; k += 64) s += rb[k] * wd[(size_t)k * 18 + o];
#pragma unroll
  for (int off = 32; off; off >>= 1) s += __shfl_xor(s, off, 64);
  if (lane == 0) geo[b * 18 + o] = s + bd[o];
}

// ---------------------------------------------------------------- TPS
__device__ __forceinline__ float tps_u(float r) { return r * r * logf(r + 1e-6f); }

__global__ __launch_bounds__(64) void tps_k(const float* __restrict__ geo,
                                            float* __restrict__ axb,
                                            float* __restrict__ ayb) {
  const int b = blockIdx.x;
  __shared__ float sDstX[9], sDstY[9];
  __shared__ float sWx[9], sWy[9];
  __shared__ float sAx[3], sAy[3];
  if (threadIdx.x == 0) {
    const float srcx[9] = {0.f, 0.5f, 1.f, 0.f, 0.5f, 1.f, 0.f, 5.f, 1.f};
    const float srcy[9] = {0.f, 0.f, 0.f, 0.5f, 0.5f, 0.5f, 1.f, 1.f, 1.f};
    float dx[9], dy[9];
    float M[12][14];
    for (int r = 0; r < 12; ++r)
      for (int cc = 0; cc < 14; ++cc) M[r][cc] = 0.f;
    for (int p = 0; p < 9; ++p) {
      const float mx = geo[b * 18 + 2 * p], my = geo[b * 18 + 2 * p + 1];
      dx[p] = srcx[p] + mx;
      dy[p] = srcy[p] + my;
      M[p][12] = -mx;
      M[p][13] = -my;
    }
    for (int p = 0; p < 9; ++p) {
      for (int q = 0; q < 9; ++q) {
        const float ddx = dx[p] - dx[q], ddy = dy[p] - dy[q];
        const float r = sqrtf(ddx * ddx + ddy * ddy + 1e-12f);
        M[p][q] = tps_u(r);
      }
      M[p][9] = 1.f;  M[p][10] = dx[p]; M[p][11] = dy[p];
      M[9][p] = 1.f;  M[10][p] = dx[p]; M[11][p] = dy[p];
    }
    for (int k = 0; k < 12; ++k) {
      int piv = k;
      float best = fabsf(M[k][k]);
      for (int r = k + 1; r < 12; ++r) {
        const float v = fabsf(M[r][k]);
        if (v > best) { best = v; piv = r; }
      }
      if (piv != k)
        for (int cc = k; cc < 14; ++cc) {
          const float tmp = M[k][cc]; M[k][cc] = M[piv][cc]; M[piv][cc] = tmp;
        }
      const float d = M[k][k];
      for (int r = k + 1; r < 12; ++r) {
        const float f = M[r][k] / d;
        for (int cc = k; cc < 14; ++cc) M[r][cc] -= f * M[k][cc];
      }
    }
    float thx[12], thy[12];
    for (int k = 11; k >= 0; --k) {
      float sx = M[k][12], sy = M[k][13];
      for (int cc = k + 1; cc < 12; ++cc) {
        sx -= M[k][cc] * thx[cc];
        sy -= M[k][cc] * thy[cc];
      }
      thx[k] = sx / M[k][k];
      thy[k] = sy / M[k][k];
    }
    float swx = 0.f, swy = 0.f;
    for (int p = 1; p < 9; ++p) {
      sWx[p] = thx[p]; sWy[p] = thy[p];
      swx += thx[p];   swy += thy[p];
    }
    sWx[0] = -swx; sWy[0] = -swy;
    for (int p = 0; p < 3; ++p) { sAx[p] = thx[9 + p]; sAy[p] = thy[9 + p]; }
    for (int p = 0; p < 9; ++p) { sDstX[p] = dx[p]; sDstY[p] = dy[p]; }
  }
  __syncthreads();
  for (int p = threadIdx.x; p < 256; p += 64) {
    const int pi = p >> 4, pj = p & 15;
    const float x = pj * (1.f / 15.f), y = pi * (1.f / 15.f);
    float zx = sAx[0] + x * sAx[1] + y * sAx[2];
    float zy = sAy[0] + x * sAy[1] + y * sAy[2];
#pragma unroll
    for (int c = 0; c < 9; ++c) {
      const float ddx = x - sDstX[c], ddy = y - sDstY[c];
      const float r = sqrtf(ddx * ddx + ddy * ddy + 1e-12f);
      const float u = tps_u(r);
      zx += u * sWx[c];
      zy += u * sWy[c];
    }
    axb[b * 256 + p] = (x + zx) * 15.f;
    ayb[b * 256 + p] = (y + zy) * 15.f;
  }
}

// ---------------------------------------------------------------- masked sum
__global__ __launch_bounds__(256) void masksum_k(const float* __restrict__ corr,
                                                 const float* __restrict__ axb,
                                                 const float* __restrict__ ayb,
                                                 float* __restrict__ out) {
  const int b = blockIdx.x;
  const int pB = threadIdx.x;
  const float ax = axb[b * 256 + pB];
  const float ay = ayb[b * 256 + pB];
  const float* __restrict__ cb = corr + (size_t)b * 65536;
  float s = 0.f;
  for (int i = 0; i < 16; ++i) {
    if (fabsf((float)i - ay) <= 1.0f) {
      const float* __restrict__ ci = cb + (size_t)i * 16 * 256 + pB;
      for (int j = 0; j < 16; ++j) {
        if (fabsf((float)j - ax) <= 1.0f) s += ci[(size_t)j * 256];
      }
    }
  }
  __shared__ float sm[256];
  sm[pB] = s;
  __syncthreads();
  for (int off = 128; off; off >>= 1) {
    if (pB < off) sm[pB] += sm[pB + off];
    __syncthreads();
  }
  if (pB == 0) out[b] = sm[0];
}

// ---------------------------------------------------------------- launch
extern "C" void kernel_launch(void* const* d_in, const int* in_sizes, int n_in,
                              void* d_out, int out_size, void* d_ws, size_t ws_size,
                              hipStream_t stream) {
  const float* imgA = (const float*)d_in[0];
  const float* imgB = (const float*)d_in[1];
  const float* W1 = (const float*)d_in[2];
  const float* W2 = (const float*)d_in[3];
  const float* W3 = (const float*)d_in[4];
  const float* W4 = (const float*)d_in[5];
  const float* Wr1 = (const float*)d_in[6];
  const float* Wr2 = (const float*)d_in[7];
  const float* Wd = (const float*)d_in[8];
  const float* bd = (const float*)d_in[9];

  float* ws = (float*)d_ws;
  unsigned short* WT2h = (unsigned short*)(ws + 0);
  unsigned short* WT3h = (unsigned short*)(ws + 73728);
  unsigned short* WT4h = (unsigned short*)(ws + 368640);
  unsigned short* WTr1h = (unsigned short*)(ws + 1548288);
  unsigned short* WTr2h = (unsigned short*)(ws + 3153920);
  unsigned short* FEATh = (unsigned short*)(ws + 3358720);
  unsigned short* S1h = (unsigned short*)(ws + 11747328);

  const bool big = (ws_size / 4) >= (36913152 + 1024);

  // weight split+transpose (shared)
  wt_k<<<288, 256, 0, stream>>>(W2, WT2h, 576, 128);
  wt_k<<<1152, 256, 0, stream>>>(W3, WT3h, 1152, 256);
  wt_k<<<4608, 256, 0, stream>>>(W4, WT4h, 2304, 512);
  wt_k<<<6272, 256, 0, stream>>>(Wr1, WTr1h, 12544, 128);
  wt_k<<<800, 256, 0, stream>>>(Wr2, WTr2h, 3200, 64);

  float* CORRf;
  unsigned short* CORRh;
  float* R1p;
  unsigned short* R1h;
  float* R2p;
  float* R2f;
  float* GEOb;
  float* AXb;
  float* AYb;

  if (big) {
    // primary: per-image full-batch conv3/conv4
    unsigned short* S3h = (unsigned short*)(ws + 11747328);  // overlays S1
    unsigned short* S2h = (unsigned short*)(ws + 20135936);
    CORRf = ws + 20135936;  // overlays S2 after feature chain
    CORRh = (unsigned short*)(ws + 22233088);
    R1p = ws + 24330240;
    R1h = (unsigned short*)(ws + 27197440);
    R2p = ws + 27607040;
    R2f = ws + 29450240;
    GEOb = ws + 29523968;
    AXb = ws + 29524544;
    AYb = ws + 29532736;

    for (int img = 0; img < 2; ++img) {
      const float* src = img ? imgB : imgA;
      for (int ci = 0; ci < 4; ++ci) {
        conv1_k<<<dim3(32, 128, 8), 64, 0, stream>>>(src + (size_t)ci * 1572864,
                                                     W1, S1h, 8388608);
        gemm_conv<2, 4, 64, 128, 3, 3, 2, 1, 0, 1, 0, 0, 1>
            <<<dim3(256, 2, 1), 256, 0, stream>>>(S1h, WT2h,
                                                  S2h + (size_t)ci * 4194304,
                                                  nullptr, 128, 128, 64, 64,
                                                  8388608, 73728, 16777216);
      }
      gemm_conv<4, 4, 128, 256, 3, 3, 2, 1, 0, 1, 0, 0, 1>
          <<<dim3(128, 4, 1), 256, 0, stream>>>(S2h, WT3h, S3h, nullptr,
                                                64, 64, 32, 32,
                                                16777216, 294912, 8388608);
      gemm_conv<2, 4, 256, 512, 3, 3, 2, 1, 0, 1, 0, 0, 1>
          <<<dim3(64, 8, 1), 256, 0, stream>>>(S3h, WT4h,
                                               FEATh + (size_t)img * 4194304,
                                               nullptr, 32, 32, 16, 16,
                                               8388608, 1179648, 8388608);
    }
  } else {
    // fallback: round-3 chunked layout (known 105.7 MB)
    unsigned short* S2h = (unsigned short*)(ws + 20135936);
    unsigned short* S3h = (unsigned short*)(ws + 24330240);
    CORRf = ws + 11747328;  // overlays S1 after feature chain
    CORRh = (unsigned short*)(ws + 13844480);
    R1p = ws + 15941632;
    R1h = (unsigned short*)(ws + 18808832);
    R2p = ws + 19218432;
    R2f = ws + 21061632;
    GEOb = ws + 21135360;
    AXb = ws + 21135936;
    AYb = ws + 21144128;

    for (int img = 0; img < 2; ++img) {
      const float* src = img ? imgB : imgA;
      for (int ci = 0; ci < 4; ++ci) {
        conv1_k<<<dim3(32, 128, 8), 64, 0, stream>>>(src + (size_t)ci * 1572864,
                                                     W1, S1h, 8388608);
        gemm_conv<2, 4, 64, 128, 3, 3, 2, 1, 0, 1, 0, 0, 1>
            <<<dim3(256, 2, 1), 256, 0, stream>>>(S1h, WT2h, S2h, nullptr,
                                                  128, 128, 64, 64,
                                                  8388608, 73728, 4194304);
        gemm_conv<4, 4, 128, 256, 3, 3, 2, 1, 0, 1, 0, 0, 1>
            <<<dim3(32, 4, 1), 256, 0, stream>>>(S2h, WT3h, S3h, nullptr,
                                                 64, 64, 32, 32,
                                                 4194304, 294912, 2097152);
        gemm_conv<2, 4, 256, 512, 3, 3, 2, 1, 0, 1, 0, 0, 1>
            <<<dim3(16, 8, 1), 256, 0, stream>>>(
                S3h, WT4h, FEATh + (size_t)img * 4194304 + (size_t)ci * 1048576,
                nullptr, 32, 32, 16, 16, 2097152, 1179648, 8388608);
      }
    }
  }

  l2norm_h<<<16384, 64, 0, stream>>>(FEATh, 8388608);
  // corr: A = FA, B = FB rows (batched), fp32 + hi/lo out
  gemm_conv<1, 4, 512, 256, 1, 1, 1, 0, 0, 0, 1, 1, 1>
      <<<dim3(128, 4, 1), 256, 0, stream>>>(FEATh, FEATh + 4194304, CORRh, CORRf,
                                            16, 16, 16, 16,
                                            8388608, 8388608, 2097152);
  // conv_r1 split-K over 49 taps, 7 slices
  gemm_conv<2, 4, 256, 128, 7, 7, 1, 0, 1, 0, 0, 0, 7>
      <<<dim3(25, 2, 7), 256, 0, stream>>>(CORRh, WTr1h, nullptr, R1p,
                                           16, 16, 10, 10,
                                           2097152, 1605632, 0);
  sum_relu_h<<<1600, 256, 0, stream>>>(R1p, R1h, 409600, 7, 409600);
  // conv_r2 split-K over 25 taps, 25 slices
  gemm_conv<1, 4, 128, 64, 5, 5, 1, 0, 1, 0, 0, 0, 25>
      <<<dim3(18, 1, 25), 256, 0, stream>>>(R1h, WTr2h, nullptr, R2p,
                                            10, 10, 6, 6,
                                            409600, 204800, 0);
  sum_relu_f<<<288, 256, 0, stream>>>(R2p, R2f, 73728, 25);
  dense_k<<<dim3(18, 32), 64, 0, stream>>>(R2f, Wd, bd, GEOb);
  tps_k<<<32, 64, 0, stream>>>(GEOb, AXb, AYb);
  masksum_k<<<32, 256, 0, stream>>>(CORRf, AXb, AYb, (float*)d_out);
}

// Round 5
// 1273.247 us; speedup vs baseline: 8.5879x; 1.3350x over previous
//
#include <hip/hip_runtime.h>
#include <math.h>

// ---------------------------------------------------------------------------
// fp16 MFMA pipeline (round 5).
//   Feature chain conv2/3/4: SINGLE-plane fp16 MFMA (1 MFMA vs round-4's 3
//     split-bf16 MFMAs, half the loads) — fp16's 11 mantissa bits give ~8x
//     less rounding noise than bf16; round-1 all-bf16 absmax was 32 -> ~4.
//   corr / conv_r1 / conv_r2: SPLIT fp16 (hi+lo planes, 3 MFMAs) ~ fp32.
//   conv1 fp32 compute -> fp16 out. dense/tps/masksum fp32.
//   Occupancy: conv1/conv2 full-image (conv2 grid 2048 blocks = 8 waves/SIMD),
//   conv3 1024, conv4 1024, corr 512, conv_r1 700, conv_r2 450 blocks.
//
// Primary layout (float units), peak 31,944,704 fl = 127.8 MB:
//   W: WT2@0(36864) WT3@36864(147456) WT4@184320(589824)
//      WTr1@774144(1605632,split) WTr2@2379776(204800,split) -> 2584576
//   FEATs @2584576 (4194304)   single fp16, 2 img x 8192 pos x 512
//   S1 @6778880 (16777216)     full img; S3 overlays same base (4194304)
//   S2 @23556096 (8388608)     full img; FEATsplit overlays after img1 conv3
//   post-chain overlay of S1 region:
//     CORRf@6778880(2097152) CORRh@8876032(2097152,split fp16)
//     R1p@10973184(7x409600) R1h@13840384(409600,split) R2p@14249984(25x73728)
//     R2f@16093184 GEO@16166912 AX@16167488 AY@16175680
// Fallback (chunked, peak 98.3 MB) if ws < 128 MB.
// ---------------------------------------------------------------------------

typedef __attribute__((ext_vector_type(8))) _Float16 f16x8;
typedef __attribute__((ext_vector_type(4))) float f32x4;

__device__ __forceinline__ unsigned short f2h(float f) {
  return __builtin_bit_cast(unsigned short, (_Float16)f);
}
__device__ __forceinline__ float h2f(unsigned short u) {
  return (float)__builtin_bit_cast(_Float16, u);
}

// ---------------------------------------------------------------- weight prep
// single fp16: wt[o][k] = fp16(w[k][o])
__global__ __launch_bounds__(256) void wt_single(const float* __restrict__ w,
                                                 unsigned short* __restrict__ wt,
                                                 int K, int C) {
  const int idx = blockIdx.x * 256 + threadIdx.x;
  if (idx < K * C) {
    const int k = idx / C, o = idx % C;
    wt[(size_t)o * K + k] = f2h(w[idx]);
  }
}
// split fp16: hi plane + lo plane at +K*C
__global__ __launch_bounds__(256) void wt_split(const float* __restrict__ w,
                                                unsigned short* __restrict__ wt,
                                                int K, int C) {
  const int idx = blockIdx.x * 256 + threadIdx.x;
  if (idx < K * C) {
    const int k = idx / C, o = idx % C;
    const float v = w[idx];
    const unsigned short hi = f2h(v);
    wt[(size_t)o * K + k] = hi;
    wt[(size_t)K * C + (size_t)o * K + k] = f2h(v - h2f(hi));
  }
}

// ---------------------------------------------------------------- conv1
// (Bc,256,256,3) fp32 -> (Bc,128,128,64) fp16 single, stride2 SAME + relu.
__global__ __launch_bounds__(64) void conv1_k(const float* __restrict__ in,
                                              const float* __restrict__ w,
                                              unsigned short* __restrict__ out) {
  const int o = threadIdx.x;
  const int j0 = blockIdx.x * 4;
  const int i = blockIdx.y;
  const int b = blockIdx.z;
  const float* __restrict__ inb = in + (size_t)b * 256 * 256 * 3;
  float acc[4] = {0.f, 0.f, 0.f, 0.f};
  const bool full = (2 * j0 + 8) < 256;
#pragma unroll
  for (int di = 0; di < 3; ++di) {
    const int y = 2 * i + di;
    if (y < 256) {
      const float* __restrict__ row = inb + ((size_t)y * 256 + 2 * j0) * 3;
      float xf[28];
      if (full) {
#pragma unroll
        for (int q = 0; q < 14; ++q) {
          const float2 v = ((const float2*)row)[q];
          xf[2 * q] = v.x; xf[2 * q + 1] = v.y;
        }
      } else {
#pragma unroll
        for (int q = 0; q < 12; ++q) {
          const float2 v = ((const float2*)row)[q];
          xf[2 * q] = v.x; xf[2 * q + 1] = v.y;
        }
        xf[24] = xf[25] = xf[26] = xf[27] = 0.f;
      }
#pragma unroll
      for (int c = 0; c < 3; ++c)
#pragma unroll
        for (int dj = 0; dj < 3; ++dj) {
          const float wv = w[(size_t)(((di * 3 + dj) * 3) + c) * 64 + o];
#pragma unroll
          for (int t = 0; t < 4; ++t) acc[t] += xf[(2 * t + dj) * 3 + c] * wv;
        }
    }
  }
#pragma unroll
  for (int t = 0; t < 4; ++t)
    out[(((size_t)b * 128 + i) * 128 + j0 + t) * 64 + o] = f2h(fmaxf(acc[t], 0.f));
}

// ---------------------------------------------------------------- MFMA conv
// Implicit GEMM: out[m][n] = sum_k A[m][k]*Wt[n][k].
// SPLIT=0: single fp16 planes, 1 MFMA.  SPLIT=1: hi/lo planes (aLo/bLo), 3 MFMAs.
template <int MT, int NT, int CIN, int COUT, int KH, int KW, int STRIDE,
          int SAMEPAD, int SPLITK, int RELU, int BATB, int OUTF32, int SK,
          int SPLIT>
__global__ __launch_bounds__(256) void gemm_conv(
    const unsigned short* __restrict__ in, const unsigned short* __restrict__ wt,
    unsigned short* __restrict__ outh, float* __restrict__ outf,
    int Hin, int Win, int Hout, int Wout, int aLo, int bLo, int oLo) {
  const int KTOT = KH * KW * CIN;
  const int lane = threadIdx.x & 63;
  const int wid = threadIdx.x >> 6;
  const int lrow = lane & 15;
  const int quad = lane >> 4;
  const int m0 = (blockIdx.x * 4 + wid) * (16 * MT);
  const int n0 = blockIdx.y * (16 * NT);

  int pix[MT], i2a[MT], j2a[MT];
#pragma unroll
  for (int mi = 0; mi < MT; ++mi) {
    const int m = m0 + mi * 16 + lrow;
    const int j = m % Wout;
    const int t = m / Wout;
    const int i = t % Hout;
    const int b = t / Hout;
    i2a[mi] = STRIDE * i;
    j2a[mi] = STRIDE * j;
    pix[mi] = (b * Hin + i2a[mi]) * Win + j2a[mi];
  }
  const unsigned short* wb = wt;
  if (BATB) wb += (size_t)(m0 / (Hout * Wout)) * COUT * KTOT;
  const unsigned short* brow[NT];
#pragma unroll
  for (int ni = 0; ni < NT; ++ni)
    brow[ni] = wb + (size_t)(n0 + ni * 16 + lrow) * KTOT + quad * 8;

  const f32x4 zf = {0.f, 0.f, 0.f, 0.f};
  const f16x8 zh = {0, 0, 0, 0, 0, 0, 0, 0};
  f32x4 acc[MT][NT];
#pragma unroll
  for (int mi = 0; mi < MT; ++mi)
#pragma unroll
    for (int ni = 0; ni < NT; ++ni) acc[mi][ni] = zf;

  int tap_lo = 0, tap_hi = KH * KW;
  if (SPLITK) {
    tap_lo = (int)blockIdx.z * KH * KW / SK;
    tap_hi = ((int)blockIdx.z + 1) * KH * KW / SK;
  }
  for (int tap = tap_lo; tap < tap_hi; ++tap) {
    const int di = tap / KW, dj = tap % KW;
    const unsigned short* ap[MT];
    bool av[MT];
#pragma unroll
    for (int mi = 0; mi < MT; ++mi) {
      av[mi] = !SAMEPAD || ((i2a[mi] + di < Hin) && (j2a[mi] + dj < Win));
      ap[mi] = in + ((size_t)pix[mi] + di * Win + dj) * CIN + quad * 8;
    }
    const int ko = tap * CIN;
#pragma unroll
    for (int c0 = 0; c0 < CIN; c0 += 32) {
      f16x8 ah[MT], bh[NT];
#pragma unroll
      for (int mi = 0; mi < MT; ++mi)
        ah[mi] = av[mi] ? *(const f16x8*)(ap[mi] + c0) : zh;
#pragma unroll
      for (int ni = 0; ni < NT; ++ni)
        bh[ni] = *(const f16x8*)(brow[ni] + ko + c0);
      if (SPLIT) {
        f16x8 al[MT], bl[NT];
#pragma unroll
        for (int mi = 0; mi < MT; ++mi)
          al[mi] = av[mi] ? *(const f16x8*)(ap[mi] + aLo + c0) : zh;
#pragma unroll
        for (int ni = 0; ni < NT; ++ni)
          bl[ni] = *(const f16x8*)(brow[ni] + bLo + ko + c0);
#pragma unroll
        for (int mi = 0; mi < MT; ++mi)
#pragma unroll
          for (int ni = 0; ni < NT; ++ni) {
            acc[mi][ni] = __builtin_amdgcn_mfma_f32_16x16x32_f16(ah[mi], bl[ni],
                                                                 acc[mi][ni], 0, 0, 0);
            acc[mi][ni] = __builtin_amdgcn_mfma_f32_16x16x32_f16(al[mi], bh[ni],
                                                                 acc[mi][ni], 0, 0, 0);
            acc[mi][ni] = __builtin_amdgcn_mfma_f32_16x16x32_f16(ah[mi], bh[ni],
                                                                 acc[mi][ni], 0, 0, 0);
          }
      } else {
#pragma unroll
        for (int mi = 0; mi < MT; ++mi)
#pragma unroll
          for (int ni = 0; ni < NT; ++ni)
            acc[mi][ni] = __builtin_amdgcn_mfma_f32_16x16x32_f16(ah[mi], bh[ni],
                                                                 acc[mi][ni], 0, 0, 0);
      }
    }
  }
  const size_t slice = SPLITK ? (size_t)blockIdx.z * ((size_t)gridDim.x * 64 * MT * COUT) : 0;
#pragma unroll
  for (int mi = 0; mi < MT; ++mi)
#pragma unroll
    for (int ni = 0; ni < NT; ++ni)
#pragma unroll
      for (int r = 0; r < 4; ++r) {
        const int row = m0 + mi * 16 + quad * 4 + r;
        const int col = n0 + ni * 16 + lrow;
        const size_t idx = (size_t)row * COUT + col;
        float v = acc[mi][ni][r];
        if (SPLITK) {
          outf[slice + idx] = v;
        } else if (OUTF32) {
          outf[idx] = v;
          const unsigned short hi = f2h(v);
          outh[idx] = hi;
          outh[(size_t)oLo + idx] = f2h(v - h2f(hi));
        } else {
          if (RELU) v = fmaxf(v, 0.f);
          outh[idx] = f2h(v);
        }
      }
}

// ---------------------------------------------------------------- split-K epi
__global__ __launch_bounds__(256) void sum_relu_h(const float* __restrict__ p,
                                                  unsigned short* __restrict__ o,
                                                  int n, int parts, int oLo) {
  const int idx = blockIdx.x * 256 + threadIdx.x;
  if (idx < n) {
    float v = 0.f;
    for (int s = 0; s < parts; ++s) v += p[(size_t)s * n + idx];
    v = fmaxf(v, 0.f);
    const unsigned short hi = f2h(v);
    o[idx] = hi;
    o[(size_t)oLo + idx] = f2h(v - h2f(hi));
  }
}
__global__ __launch_bounds__(256) void sum_relu_f(const float* __restrict__ p,
                                                  float* __restrict__ o,
                                                  int n, int parts) {
  const int idx = blockIdx.x * 256 + threadIdx.x;
  if (idx < n) {
    float v = 0.f;
    for (int s = 0; s < parts; ++s) v += p[(size_t)s * n + idx];
    o[idx] = fmaxf(v, 0.f);
  }
}

// ---------------------------------------------------------------- l2 normalize
// in: single fp16 (pos,512); out: split fp16 hi @y, lo @y+loOff.
__global__ __launch_bounds__(64) void l2norm_k(const unsigned short* __restrict__ x,
                                               unsigned short* __restrict__ y,
                                               int loOff) {
  const int lane = threadIdx.x;
  const f16x8 v = *(const f16x8*)(x + (size_t)blockIdx.x * 512 + lane * 8);
  float f[8];
  float s = 0.f;
#pragma unroll
  for (int k = 0; k < 8; ++k) {
    f[k] = (float)v[k];
    s += f[k] * f[k];
  }
#pragma unroll
  for (int off = 32; off; off >>= 1) s += __shfl_xor(s, off, 64);
  const float inv = 1.f / (sqrtf(s) + 1e-6f);
  f16x8 vh, vl;
#pragma unroll
  for (int k = 0; k < 8; ++k) {
    const float nv = f[k] * inv;
    const _Float16 hi = (_Float16)nv;
    vh[k] = hi;
    vl[k] = (_Float16)(nv - (float)hi);
  }
  unsigned short* ph = y + (size_t)blockIdx.x * 512 + lane * 8;
  *(f16x8*)ph = vh;
  *(f16x8*)(ph + (size_t)loOff) = vl;
}

// ---------------------------------------------------------------- dense
__global__ __launch_bounds__(64) void dense_k(const float* __restrict__ r2,
                                              const float* __restrict__ wd,
                                              const float* __restrict__ bd,
                                              float* __restrict__ geo) {
  const int o = blockIdx.x;
  const int b = blockIdx.y;
  const int lane = threadIdx.x;
  const float* __restrict__ rb = r2 + (size_t)b * 2304;
  float s = 0.f;
  for (int k = lane; k < 2304; k += 64) s += rb[k] * wd[(size_t)k * 18 + o];
#pragma unroll
  for (int off = 32; off; off >>= 1) s += __shfl_xor(s, off, 64);
  if (lane == 0) geo[b * 18 + o] = s + bd[o];
}

// ---------------------------------------------------------------- TPS
__device__ __forceinline__ float tps_u(float r) { return r * r * logf(r + 1e-6f); }

__global__ __launch_bounds__(64) void tps_k(const float* __restrict__ geo,
                                            float* __restrict__ axb,
                                            float* __restrict__ ayb) {
  const int b = blockIdx.x;
  __shared__ float sDstX[9], sDstY[9];
  __shared__ float sWx[9], sWy[9];
  __shared__ float sAx[3], sAy[3];
  if (threadIdx.x == 0) {
    const float srcx[9] = {0.f, 0.5f, 1.f, 0.f, 0.5f, 1.f, 0.f, 5.f, 1.f};
    const float srcy[9] = {0.f, 0.f, 0.f, 0.5f, 0.5f, 0.5f, 1.f, 1.f, 1.f};
    float dx[9], dy[9];
    float M[12][14];
    for (int r = 0; r < 12; ++r)
      for (int cc = 0; cc < 14; ++cc) M[r][cc] = 0.f;
    for (int p = 0; p < 9; ++p) {
      const float mx = geo[b * 18 + 2 * p], my = geo[b * 18 + 2 * p + 1];
      dx[p] = srcx[p] + mx;
      dy[p] = srcy[p] + my;
      M[p][12] = -mx;
      M[p][13] = -my;
    }
    for (int p = 0; p < 9; ++p) {
      for (int q = 0; q < 9; ++q) {
        const float ddx = dx[p] - dx[q], ddy = dy[p] - dy[q];
        const float r = sqrtf(ddx * ddx + ddy * ddy + 1e-12f);
        M[p][q] = tps_u(r);
      }
      M[p][9] = 1.f;  M[p][10] = dx[p]; M[p][11] = dy[p];
      M[9][p] = 1.f;  M[10][p] = dx[p]; M[11][p] = dy[p];
    }
    for (int k = 0; k < 12; ++k) {
      int piv = k;
      float best = fabsf(M[k][k]);
      for (int r = k + 1; r < 12; ++r) {
        const float v = fabsf(M[r][k]);
        if (v > best) { best = v; piv = r; }
      }
      if (piv != k)
        for (int cc = k; cc < 14; ++cc) {
          const float tmp = M[k][cc]; M[k][cc] = M[piv][cc]; M[piv][cc] = tmp;
        }
      const float d = M[k][k];
      for (int r = k + 1; r < 12; ++r) {
        const float f = M[r][k] / d;
        for (int cc = k; cc < 14; ++cc) M[r][cc] -= f * M[k][cc];
      }
    }
    float thx[12], thy[12];
    for (int k = 11; k >= 0; --k) {
      float sx = M[k][12], sy = M[k][13];
      for (int cc = k + 1; cc < 12; ++cc) {
        sx -= M[k][cc] * thx[cc];
        sy -= M[k][cc] * thy[cc];
      }
      thx[k] = sx / M[k][k];
      thy[k] = sy / M[k][k];
    }
    float swx = 0.f, swy = 0.f;
    for (int p = 1; p < 9; ++p) {
      sWx[p] = thx[p]; sWy[p] = thy[p];
      swx += thx[p];   swy += thy[p];
    }
    sWx[0] = -swx; sWy[0] = -swy;
    for (int p = 0; p < 3; ++p) { sAx[p] = thx[9 + p]; sAy[p] = thy[9 + p]; }
    for (int p = 0; p < 9; ++p) { sDstX[p] = dx[p]; sDstY[p] = dy[p]; }
  }
  __syncthreads();
  for (int p = threadIdx.x; p < 256; p += 64) {
    const int pi = p >> 4, pj = p & 15;
    const float x = pj * (1.f / 15.f), y = pi * (1.f / 15.f);
    float zx = sAx[0] + x * sAx[1] + y * sAx[2];
    float zy = sAy[0] + x * sAy[1] + y * sAy[2];
#pragma unroll
    for (int c = 0; c < 9; ++c) {
      const float ddx = x - sDstX[c], ddy = y - sDstY[c];
      const float r = sqrtf(ddx * ddx + ddy * ddy + 1e-12f);
      const float u = tps_u(r);
      zx += u * sWx[c];
      zy += u * sWy[c];
    }
    axb[b * 256 + p] = (x + zx) * 15.f;
    ayb[b * 256 + p] = (y + zy) * 15.f;
  }
}

// ---------------------------------------------------------------- masked sum
__global__ __launch_bounds__(256) void masksum_k(const float* __restrict__ corr,
                                                 const float* __restrict__ axb,
                                                 const float* __restrict__ ayb,
                                                 float* __restrict__ out) {
  const int b = blockIdx.x;
  const int pB = threadIdx.x;
  const float ax = axb[b * 256 + pB];
  const float ay = ayb[b * 256 + pB];
  const float* __restrict__ cb = corr + (size_t)b * 65536;
  float s = 0.f;
  for (int i = 0; i < 16; ++i) {
    if (fabsf((float)i - ay) <= 1.0f) {
      const float* __restrict__ ci = cb + (size_t)i * 16 * 256 + pB;
      for (int j = 0; j < 16; ++j) {
        if (fabsf((float)j - ax) <= 1.0f) s += ci[(size_t)j * 256];
      }
    }
  }
  __shared__ float sm[256];
  sm[pB] = s;
  __syncthreads();
  for (int off = 128; off; off >>= 1) {
    if (pB < off) sm[pB] += sm[pB + off];
    __syncthreads();
  }
  if (pB == 0) out[b] = sm[0];
}

// ---------------------------------------------------------------- launch
extern "C" void kernel_launch(void* const* d_in, const int* in_sizes, int n_in,
                              void* d_out, int out_size, void* d_ws, size_t ws_size,
                              hipStream_t stream) {
  const float* imgA = (const float*)d_in[0];
  const float* imgB = (const float*)d_in[1];
  const float* W1 = (const float*)d_in[2];
  const float* W2 = (const float*)d_in[3];
  const float* W3 = (const float*)d_in[4];
  const float* W4 = (const float*)d_in[5];
  const float* Wr1 = (const float*)d_in[6];
  const float* Wr2 = (const float*)d_in[7];
  const float* Wd = (const float*)d_in[8];
  const float* bd = (const float*)d_in[9];

  float* ws = (float*)d_ws;
  unsigned short* WT2 = (unsigned short*)(ws + 0);
  unsigned short* WT3 = (unsigned short*)(ws + 36864);
  unsigned short* WT4 = (unsigned short*)(ws + 184320);
  unsigned short* WTr1 = (unsigned short*)(ws + 774144);
  unsigned short* WTr2 = (unsigned short*)(ws + 2379776);
  unsigned short* FEATs = (unsigned short*)(ws + 2584576);

  // weight prep (shared)
  wt_single<<<288, 256, 0, stream>>>(W2, WT2, 576, 128);
  wt_single<<<1152, 256, 0, stream>>>(W3, WT3, 1152, 256);
  wt_single<<<4608, 256, 0, stream>>>(W4, WT4, 2304, 512);
  wt_split<<<6272, 256, 0, stream>>>(Wr1, WTr1, 12544, 128);
  wt_split<<<800, 256, 0, stream>>>(Wr2, WTr2, 3200, 64);

  const bool big = (ws_size / 4) >= (31944704 + 4096);

  unsigned short *FEATsp, *CORRh, *R1h;
  float *CORRf, *R1p, *R2p, *R2f, *GEOb, *AXb, *AYb;

  if (big) {
    unsigned short* S1 = (unsigned short*)(ws + 6778880);
    unsigned short* S3 = (unsigned short*)(ws + 6778880);   // overlays S1
    unsigned short* S2 = (unsigned short*)(ws + 23556096);
    FEATsp = (unsigned short*)(ws + 23556096);              // overlays S2
    CORRf = ws + 6778880;                                   // overlays S1/S3
    CORRh = (unsigned short*)(ws + 8876032);
    R1p = ws + 10973184;
    R1h = (unsigned short*)(ws + 13840384);
    R2p = ws + 14249984;
    R2f = ws + 16093184;
    GEOb = ws + 16166912;
    AXb = ws + 16167488;
    AYb = ws + 16175680;

    for (int img = 0; img < 2; ++img) {
      const float* src = img ? imgB : imgA;
      conv1_k<<<dim3(32, 128, 32), 64, 0, stream>>>(src, W1, S1);
      gemm_conv<2, 4, 64, 128, 3, 3, 2, 1, 0, 1, 0, 0, 1, 0>
          <<<dim3(1024, 2, 1), 256, 0, stream>>>(S1, WT2, S2, nullptr,
                                                 128, 128, 64, 64, 0, 0, 0);
      gemm_conv<2, 4, 128, 256, 3, 3, 2, 1, 0, 1, 0, 0, 1, 0>
          <<<dim3(256, 4, 1), 256, 0, stream>>>(S2, WT3, S3, nullptr,
                                                64, 64, 32, 32, 0, 0, 0);
      gemm_conv<1, 4, 256, 512, 3, 3, 2, 1, 0, 1, 0, 0, 1, 0>
          <<<dim3(128, 8, 1), 256, 0, stream>>>(S3, WT4,
                                                FEATs + (size_t)img * 4194304,
                                                nullptr, 32, 32, 16, 16, 0, 0, 0);
    }
  } else {
    // fallback: chunked (8 batches), peak 98.3 MB
    unsigned short* S1 = (unsigned short*)(ws + 15167488);
    unsigned short* S3 = (unsigned short*)(ws + 15167488);  // overlays S1
    unsigned short* S2 = (unsigned short*)(ws + 19361792);
    FEATsp = (unsigned short*)(ws + 6778880);
    CORRf = ws + 15167488;
    CORRh = (unsigned short*)(ws + 17264640);
    R1p = ws + 19361792;
    R1h = (unsigned short*)(ws + 22228992);
    R2p = ws + 22638592;
    R2f = ws + 24481792;
    GEOb = ws + 24555520;
    AXb = ws + 24556096;
    AYb = ws + 24564288;

    for (int img = 0; img < 2; ++img) {
      const float* src = img ? imgB : imgA;
      for (int ci = 0; ci < 4; ++ci) {
        conv1_k<<<dim3(32, 128, 8), 64, 0, stream>>>(src + (size_t)ci * 1572864,
                                                     W1, S1);
        gemm_conv<2, 4, 64, 128, 3, 3, 2, 1, 0, 1, 0, 0, 1, 0>
            <<<dim3(256, 2, 1), 256, 0, stream>>>(S1, WT2, S2, nullptr,
                                                  128, 128, 64, 64, 0, 0, 0);
        gemm_conv<2, 4, 128, 256, 3, 3, 2, 1, 0, 1, 0, 0, 1, 0>
            <<<dim3(64, 4, 1), 256, 0, stream>>>(S2, WT3, S3, nullptr,
                                                 64, 64, 32, 32, 0, 0, 0);
        gemm_conv<1, 4, 256, 512, 3, 3, 2, 1, 0, 1, 0, 0, 1, 0>
            <<<dim3(32, 8, 1), 256, 0, stream>>>(
                S3, WT4, FEATs + (size_t)img * 4194304 + (size_t)ci * 1048576,
                nullptr, 32, 32, 16, 16, 0, 0, 0);
      }
    }
  }

  // l2norm: FEATs (single) -> FEATsp (split, lo at +8388608)
  l2norm_k<<<16384, 64, 0, stream>>>(FEATs, FEATsp, 8388608);
  // corr: split GEMM, A = img0 features, B = img1 features (batched rows)
  gemm_conv<1, 4, 512, 256, 1, 1, 1, 0, 0, 0, 1, 1, 1, 1>
      <<<dim3(128, 4, 1), 256, 0, stream>>>(FEATsp, FEATsp + 4194304, CORRh,
                                            CORRf, 16, 16, 16, 16,
                                            8388608, 8388608, 2097152);
  // conv_r1: split, split-K 7
  gemm_conv<2, 2, 256, 128, 7, 7, 1, 0, 1, 0, 0, 0, 7, 1>
      <<<dim3(25, 4, 7), 256, 0, stream>>>(CORRh, WTr1, nullptr, R1p,
                                           16, 16, 10, 10,
                                           2097152, 1605632, 0);
  sum_relu_h<<<1600, 256, 0, stream>>>(R1p, R1h, 409600, 7, 409600);
  // conv_r2: split, split-K 25
  gemm_conv<1, 4, 128, 64, 5, 5, 1, 0, 1, 0, 0, 0, 25, 1>
      <<<dim3(18, 1, 25), 256, 0, stream>>>(R1h, WTr2, nullptr, R2p,
                                            10, 10, 6, 6,
                                            409600, 204800, 0);
  sum_relu_f<<<288, 256, 0, stream>>>(R2p, R2f, 73728, 25);
  dense_k<<<dim3(18, 32), 64, 0, stream>>>(R2f, Wd, bd, GEOb);
  tps_k<<<32, 64, 0, stream>>>(GEOb, AXb, AYb);
  masksum_k<<<32, 256, 0, stream>>>(CORRf, AXb, AYb, (float*)d_out);
}

// Round 6
// 755.236 us; speedup vs baseline: 14.4782x; 1.6859x over previous
//
#include <hip/hip_runtime.h>
#include <math.h>

// ---------------------------------------------------------------------------
// Round 6: LDS-tiled MFMA for the feature chain (m93-style structure).
//   conv2/3/4: tile_conv — BMxBN output tile, BK=64 LDS-staged K-chunks
//     (implicit-GEMM gather in staging), 4 waves x (BM/32 x BN/32) MFMA tiles,
//     fp16 single-plane (absmax 4.0 proven in round 5).
//   conv1: fp32 vector kernel -> fp16 (half-image chunks).
//   corr / conv_r1 / conv_r2: round-5 split-fp16 direct kernels (hi+lo,
//     3xMFMA ~ fp32 accuracy for the geo path).
//
// Workspace (float units), peak 98.3 MB (< 102.7 MB proven in round 1):
//   WT2@0(36864) WT3@36864(147456) WT4@184320(589824)
//   WTr1@774144(1605632,split) WTr2@2379776(204800,split)
//   FEATs @2584576 (4194304)    single fp16, 2 img x 8192 x 512
//   S2    @6778880 (8388608)    full img 32x64x64x128 fp16
//   S1    @15167488 (8388608)   half img 16x128x128x64 fp16
//   S3    @15167488 (4194304)   full img 32x32x32x256 (overlays S1, dead)
//   post-chain: FEATsp @6778880 (8388608, split pair; overlays S2)
//     CORRf@15167488(2097152) CORRh@17264640(2097152, split pair)
//     R1p@19361792(7x409600) R1h@22228992(409600, split pair)
//     R2p@22638592(25x73728) R2f@24481792(73728)
//     GEO@24555520 AX@24556096 AY@24564288  -> end 24572480
// ---------------------------------------------------------------------------

typedef __attribute__((ext_vector_type(8))) _Float16 f16x8;
typedef __attribute__((ext_vector_type(4))) float f32x4;

__device__ __forceinline__ unsigned short f2h(float f) {
  return __builtin_bit_cast(unsigned short, (_Float16)f);
}
__device__ __forceinline__ float h2f(unsigned short u) {
  return (float)__builtin_bit_cast(_Float16, u);
}

// ---------------------------------------------------------------- weight prep
__global__ __launch_bounds__(256) void wt_single(const float* __restrict__ w,
                                                 unsigned short* __restrict__ wt,
                                                 int K, int C) {
  const int idx = blockIdx.x * 256 + threadIdx.x;
  if (idx < K * C) {
    const int k = idx / C, o = idx % C;
    wt[(size_t)o * K + k] = f2h(w[idx]);
  }
}
__global__ __launch_bounds__(256) void wt_split(const float* __restrict__ w,
                                                unsigned short* __restrict__ wt,
                                                int K, int C) {
  const int idx = blockIdx.x * 256 + threadIdx.x;
  if (idx < K * C) {
    const int k = idx / C, o = idx % C;
    const float v = w[idx];
    const unsigned short hi = f2h(v);
    wt[(size_t)o * K + k] = hi;
    wt[(size_t)K * C + (size_t)o * K + k] = f2h(v - h2f(hi));
  }
}

// ---------------------------------------------------------------- conv1
__global__ __launch_bounds__(64) void conv1_k(const float* __restrict__ in,
                                              const float* __restrict__ w,
                                              unsigned short* __restrict__ out) {
  const int o = threadIdx.x;
  const int j0 = blockIdx.x * 4;
  const int i = blockIdx.y;
  const int b = blockIdx.z;
  const float* __restrict__ inb = in + (size_t)b * 256 * 256 * 3;
  float acc[4] = {0.f, 0.f, 0.f, 0.f};
  const bool full = (2 * j0 + 8) < 256;
#pragma unroll
  for (int di = 0; di < 3; ++di) {
    const int y = 2 * i + di;
    if (y < 256) {
      const float* __restrict__ row = inb + ((size_t)y * 256 + 2 * j0) * 3;
      float xf[28];
      if (full) {
#pragma unroll
        for (int q = 0; q < 14; ++q) {
          const float2 v = ((const float2*)row)[q];
          xf[2 * q] = v.x; xf[2 * q + 1] = v.y;
        }
      } else {
#pragma unroll
        for (int q = 0; q < 12; ++q) {
          const float2 v = ((const float2*)row)[q];
          xf[2 * q] = v.x; xf[2 * q + 1] = v.y;
        }
        xf[24] = xf[25] = xf[26] = xf[27] = 0.f;
      }
#pragma unroll
      for (int c = 0; c < 3; ++c)
#pragma unroll
        for (int dj = 0; dj < 3; ++dj) {
          const float wv = w[(size_t)(((di * 3 + dj) * 3) + c) * 64 + o];
#pragma unroll
          for (int t = 0; t < 4; ++t) acc[t] += xf[(2 * t + dj) * 3 + c] * wv;
        }
    }
  }
#pragma unroll
  for (int t = 0; t < 4; ++t)
    out[(((size_t)b * 128 + i) * 128 + j0 + t) * 64 + o] = f2h(fmaxf(acc[t], 0.f));
}

// ---------------------------------------------------------------- tile conv
// LDS-tiled implicit-GEMM conv, fp16 single plane, relu out.
// out[m][n] = sum_k A[m][k]*Wt[n][k], m=(b,i,j), k=(tap,c), n=out ch.
// Block 256 thr = 4 waves (2x2), BK=64 per chunk, As/Bs padded LDA=72.
template <int BM, int BN, int CIN, int COUT, int KH, int KW, int STRIDE>
__global__ __launch_bounds__(256) void tile_conv(
    const unsigned short* __restrict__ in, const unsigned short* __restrict__ wt,
    unsigned short* __restrict__ out, int Hin, int Win, int Hout, int Wout) {
  constexpr int LDA = 72;
  constexpr int CPT = CIN / 64;       // K-chunks per tap
  constexpr int NCH = KH * KW * CPT;  // total K-chunks
  constexpr int LA = BM / 32;         // f16x8 A loads / thread
  constexpr int LB = BN / 32;
  constexpr int KTOT = KH * KW * CIN;
  constexpr int MT = BM / 32;         // MFMA tiles per wave (rows)
  constexpr int NT = BN / 32;
  __shared__ _Float16 As[BM * LDA];
  __shared__ _Float16 Bs[BN * LDA];

  const int t = threadIdx.x;
  const int lane = t & 63, wid = t >> 6;
  const int lrow = lane & 15, quad = lane >> 4;
  const int m0 = blockIdx.x * BM;
  const int n0 = blockIdx.y * BN;

  int pixB[LA], iS[LA], jS[LA], lofA[LA];
#pragma unroll
  for (int i = 0; i < LA; ++i) {
    const int u = t + 256 * i;
    const int r = u >> 3, sl = u & 7;
    const int m = m0 + r;
    const int j = m % Wout;
    const int t2 = m / Wout;
    const int ii = t2 % Hout;
    const int b = t2 / Hout;
    iS[i] = ii * STRIDE;
    jS[i] = j * STRIDE;
    pixB[i] = ((b * Hin + iS[i]) * Win + jS[i]) * CIN + sl * 8;
    lofA[i] = r * LDA + sl * 8;
  }
  int bofB[LB], lofB[LB];
#pragma unroll
  for (int i = 0; i < LB; ++i) {
    const int u = t + 256 * i;
    const int r = u >> 3, sl = u & 7;
    bofB[i] = (n0 + r) * KTOT + sl * 8;
    lofB[i] = r * LDA + sl * 8;
  }

  const f16x8 zh = {0, 0, 0, 0, 0, 0, 0, 0};
  f32x4 acc[MT][NT];
#pragma unroll
  for (int mi = 0; mi < MT; ++mi)
#pragma unroll
    for (int ni = 0; ni < NT; ++ni) acc[mi][ni] = {0.f, 0.f, 0.f, 0.f};

  const int mB = (wid >> 1) * (BM / 2);
  const int nB = (wid & 1) * (BN / 2);

  for (int ch = 0; ch < NCH; ++ch) {
    const int tap = ch / CPT;
    const int c0 = (ch % CPT) * 64;
    const int di = tap / KW, dj = tap % KW;
    const int toff = (di * Win + dj) * CIN + c0;
    const int woff = tap * CIN + c0;
    f16x8 va[LA], vb[LB];
#pragma unroll
    for (int i = 0; i < LA; ++i) {
      const bool ok = (iS[i] + di < Hin) && (jS[i] + dj < Win);
      va[i] = ok ? *(const f16x8*)(in + pixB[i] + toff) : zh;
    }
#pragma unroll
    for (int i = 0; i < LB; ++i)
      vb[i] = *(const f16x8*)(wt + bofB[i] + woff);
    __syncthreads();
#pragma unroll
    for (int i = 0; i < LA; ++i) *(f16x8*)&As[lofA[i]] = va[i];
#pragma unroll
    for (int i = 0; i < LB; ++i) *(f16x8*)&Bs[lofB[i]] = vb[i];
    __syncthreads();
#pragma unroll
    for (int ks = 0; ks < 2; ++ks) {
      f16x8 af[MT], bf[NT];
#pragma unroll
      for (int mi = 0; mi < MT; ++mi)
        af[mi] = *(const f16x8*)&As[(mB + mi * 16 + lrow) * LDA + ks * 32 + quad * 8];
#pragma unroll
      for (int ni = 0; ni < NT; ++ni)
        bf[ni] = *(const f16x8*)&Bs[(nB + ni * 16 + lrow) * LDA + ks * 32 + quad * 8];
#pragma unroll
      for (int mi = 0; mi < MT; ++mi)
#pragma unroll
        for (int ni = 0; ni < NT; ++ni)
          acc[mi][ni] = __builtin_amdgcn_mfma_f32_16x16x32_f16(af[mi], bf[ni],
                                                               acc[mi][ni], 0, 0, 0);
    }
  }
#pragma unroll
  for (int mi = 0; mi < MT; ++mi)
#pragma unroll
    for (int ni = 0; ni < NT; ++ni)
#pragma unroll
      for (int r = 0; r < 4; ++r) {
        const int row = m0 + mB + mi * 16 + quad * 4 + r;
        const int col = n0 + nB + ni * 16 + lrow;
        out[(size_t)row * COUT + col] = f2h(fmaxf(acc[mi][ni][r], 0.f));
      }
}

// ---------------------------------------------------------------- direct MFMA
// (round-5 kernel, kept for corr / conv_r1 / conv_r2)
template <int MT, int NT, int CIN, int COUT, int KH, int KW, int STRIDE,
          int SAMEPAD, int SPLITK, int RELU, int BATB, int OUTF32, int SK,
          int SPLIT>
__global__ __launch_bounds__(256) void gemm_conv(
    const unsigned short* __restrict__ in, const unsigned short* __restrict__ wt,
    unsigned short* __restrict__ outh, float* __restrict__ outf,
    int Hin, int Win, int Hout, int Wout, int aLo, int bLo, int oLo) {
  const int KTOT = KH * KW * CIN;
  const int lane = threadIdx.x & 63;
  const int wid = threadIdx.x >> 6;
  const int lrow = lane & 15;
  const int quad = lane >> 4;
  const int m0 = (blockIdx.x * 4 + wid) * (16 * MT);
  const int n0 = blockIdx.y * (16 * NT);

  int pix[MT], i2a[MT], j2a[MT];
#pragma unroll
  for (int mi = 0; mi < MT; ++mi) {
    const int m = m0 + mi * 16 + lrow;
    const int j = m % Wout;
    const int t = m / Wout;
    const int i = t % Hout;
    const int b = t / Hout;
    i2a[mi] = STRIDE * i;
    j2a[mi] = STRIDE * j;
    pix[mi] = (b * Hin + i2a[mi]) * Win + j2a[mi];
  }
  const unsigned short* wb = wt;
  if (BATB) wb += (size_t)(m0 / (Hout * Wout)) * COUT * KTOT;
  const unsigned short* brow[NT];
#pragma unroll
  for (int ni = 0; ni < NT; ++ni)
    brow[ni] = wb + (size_t)(n0 + ni * 16 + lrow) * KTOT + quad * 8;

  const f16x8 zh = {0, 0, 0, 0, 0, 0, 0, 0};
  f32x4 acc[MT][NT];
#pragma unroll
  for (int mi = 0; mi < MT; ++mi)
#pragma unroll
    for (int ni = 0; ni < NT; ++ni) acc[mi][ni] = {0.f, 0.f, 0.f, 0.f};

  int tap_lo = 0, tap_hi = KH * KW;
  if (SPLITK) {
    tap_lo = (int)blockIdx.z * KH * KW / SK;
    tap_hi = ((int)blockIdx.z + 1) * KH * KW / SK;
  }
  for (int tap = tap_lo; tap < tap_hi; ++tap) {
    const int di = tap / KW, dj = tap % KW;
    const unsigned short* ap[MT];
    bool av[MT];
#pragma unroll
    for (int mi = 0; mi < MT; ++mi) {
      av[mi] = !SAMEPAD || ((i2a[mi] + di < Hin) && (j2a[mi] + dj < Win));
      ap[mi] = in + ((size_t)pix[mi] + di * Win + dj) * CIN + quad * 8;
    }
    const int ko = tap * CIN;
#pragma unroll
    for (int c0 = 0; c0 < CIN; c0 += 32) {
      f16x8 ah[MT], bh[NT];
#pragma unroll
      for (int mi = 0; mi < MT; ++mi)
        ah[mi] = av[mi] ? *(const f16x8*)(ap[mi] + c0) : zh;
#pragma unroll
      for (int ni = 0; ni < NT; ++ni)
        bh[ni] = *(const f16x8*)(brow[ni] + ko + c0);
      if (SPLIT) {
        f16x8 al[MT], bl[NT];
#pragma unroll
        for (int mi = 0; mi < MT; ++mi)
          al[mi] = av[mi] ? *(const f16x8*)(ap[mi] + aLo + c0) : zh;
#pragma unroll
        for (int ni = 0; ni < NT; ++ni)
          bl[ni] = *(const f16x8*)(brow[ni] + bLo + ko + c0);
#pragma unroll
        for (int mi = 0; mi < MT; ++mi)
#pragma unroll
          for (int ni = 0; ni < NT; ++ni) {
            acc[mi][ni] = __builtin_amdgcn_mfma_f32_16x16x32_f16(ah[mi], bl[ni],
                                                                 acc[mi][ni], 0, 0, 0);
            acc[mi][ni] = __builtin_amdgcn_mfma_f32_16x16x32_f16(al[mi], bh[ni],
                                                                 acc[mi][ni], 0, 0, 0);
            acc[mi][ni] = __builtin_amdgcn_mfma_f32_16x16x32_f16(ah[mi], bh[ni],
                                                                 acc[mi][ni], 0, 0, 0);
          }
      } else {
#pragma unroll
        for (int mi = 0; mi < MT; ++mi)
#pragma unroll
          for (int ni = 0; ni < NT; ++ni)
            acc[mi][ni] = __builtin_amdgcn_mfma_f32_16x16x32_f16(ah[mi], bh[ni],
                                                                 acc[mi][ni], 0, 0, 0);
      }
    }
  }
  const size_t slice = SPLITK ? (size_t)blockIdx.z * ((size_t)gridDim.x * 64 * MT * COUT) : 0;
#pragma unroll
  for (int mi = 0; mi < MT; ++mi)
#pragma unroll
    for (int ni = 0; ni < NT; ++ni)
#pragma unroll
      for (int r = 0; r < 4; ++r) {
        const int row = m0 + mi * 16 + quad * 4 + r;
        const int col = n0 + ni * 16 + lrow;
        const size_t idx = (size_t)row * COUT + col;
        float v = acc[mi][ni][r];
        if (SPLITK) {
          outf[slice + idx] = v;
        } else if (OUTF32) {
          outf[idx] = v;
          const unsigned short hi = f2h(v);
          outh[idx] = hi;
          outh[(size_t)oLo + idx] = f2h(v - h2f(hi));
        } else {
          if (RELU) v = fmaxf(v, 0.f);
          outh[idx] = f2h(v);
        }
      }
}

// ---------------------------------------------------------------- split-K epi
__global__ __launch_bounds__(256) void sum_relu_h(const float* __restrict__ p,
                                                  unsigned short* __restrict__ o,
                                                  int n, int parts, int oLo) {
  const int idx = blockIdx.x * 256 + threadIdx.x;
  if (idx < n) {
    float v = 0.f;
    for (int s = 0; s < parts; ++s) v += p[(size_t)s * n + idx];
    v = fmaxf(v, 0.f);
    const unsigned short hi = f2h(v);
    o[idx] = hi;
    o[(size_t)oLo + idx] = f2h(v - h2f(hi));
  }
}
__global__ __launch_bounds__(256) void sum_relu_f(const float* __restrict__ p,
                                                  float* __restrict__ o,
                                                  int n, int parts) {
  const int idx = blockIdx.x * 256 + threadIdx.x;
  if (idx < n) {
    float v = 0.f;
    for (int s = 0; s < parts; ++s) v += p[(size_t)s * n + idx];
    o[idx] = fmaxf(v, 0.f);
  }
}

// ---------------------------------------------------------------- l2 normalize
__global__ __launch_bounds__(64) void l2norm_k(const unsigned short* __restrict__ x,
                                               unsigned short* __restrict__ y,
                                               int loOff) {
  const int lane = threadIdx.x;
  const f16x8 v = *(const f16x8*)(x + (size_t)blockIdx.x * 512 + lane * 8);
  float f[8];
  float s = 0.f;
#pragma unroll
  for (int k = 0; k < 8; ++k) {
    f[k] = (float)v[k];
    s += f[k] * f[k];
  }
#pragma unroll
  for (int off = 32; off; off >>= 1) s += __shfl_xor(s, off, 64);
  const float inv = 1.f / (sqrtf(s) + 1e-6f);
  f16x8 vh, vl;
#pragma unroll
  for (int k = 0; k < 8; ++k) {
    const float nv = f[k] * inv;
    const _Float16 hi = (_Float16)nv;
    vh[k] = hi;
    vl[k] = (_Float16)(nv - (float)hi);
  }
  unsigned short* ph = y + (size_t)blockIdx.x * 512 + lane * 8;
  *(f16x8*)ph = vh;
  *(f16x8*)(ph + (size_t)loOff) = vl;
}

// ---------------------------------------------------------------- dense
__global__ __launch_bounds__(64) void dense_k(const float* __restrict__ r2,
                                              const float* __restrict__ wd,
                                              const float* __restrict__ bd,
                                              float* __restrict__ geo) {
  const int o = blockIdx.x;
  const int b = blockIdx.y;
  const int lane = threadIdx.x;
  const float* __restrict__ rb = r2 + (size_t)b * 2304;
  float s = 0.f;
  for (int k = lane; k < 2304; k += 64) s += rb[k] * wd[(size_t)k * 18 + o];
#pragma unroll
  for (int off = 32; off; off >>= 1) s += __shfl_xor(s, off, 64);
  if (lane == 0) geo[b * 18 + o] = s + bd[o];
}

// ---------------------------------------------------------------- TPS
__device__ __forceinline__ float tps_u(float r) { return r * r * logf(r + 1e-6f); }

__global__ __launch_bounds__(64) void tps_k(const float* __restrict__ geo,
                                            float* __restrict__ axb,
                                            float* __restrict__ ayb) {
  const int b = blockIdx.x;
  __shared__ float sDstX[9], sDstY[9];
  __shared__ float sWx[9], sWy[9];
  __shared__ float sAx[3], sAy[3];
  if (threadIdx.x == 0) {
    const float srcx[9] = {0.f, 0.5f, 1.f, 0.f, 0.5f, 1.f, 0.f, 5.f, 1.f};
    const float srcy[9] = {0.f, 0.f, 0.f, 0.5f, 0.5f, 0.5f, 1.f, 1.f, 1.f};
    float dx[9], dy[9];
    float M[12][14];
    for (int r = 0; r < 12; ++r)
      for (int cc = 0; cc < 14; ++cc) M[r][cc] = 0.f;
    for (int p = 0; p < 9; ++p) {
      const float mx = geo[b * 18 + 2 * p], my = geo[b * 18 + 2 * p + 1];
      dx[p] = srcx[p] + mx;
      dy[p] = srcy[p] + my;
      M[p][12] = -mx;
      M[p][13] = -my;
    }
    for (int p = 0; p < 9; ++p) {
      for (int q = 0; q < 9; ++q) {
        const float ddx = dx[p] - dx[q], ddy = dy[p] - dy[q];
        const float r = sqrtf(ddx * ddx + ddy * ddy + 1e-12f);
        M[p][q] = tps_u(r);
      }
      M[p][9] = 1.f;  M[p][10] = dx[p]; M[p][11] = dy[p];
      M[9][p] = 1.f;  M[10][p] = dx[p]; M[11][p] = dy[p];
    }
    for (int k = 0; k < 12; ++k) {
      int piv = k;
      float best = fabsf(M[k][k]);
      for (int r = k + 1; r < 12; ++r) {
        const float v = fabsf(M[r][k]);
        if (v > best) { best = v; piv = r; }
      }
      if (piv != k)
        for (int cc = k; cc < 14; ++cc) {
          const float tmp = M[k][cc]; M[k][cc] = M[piv][cc]; M[piv][cc] = tmp;
        }
      const float d = M[k][k];
      for (int r = k + 1; r < 12; ++r) {
        const float f = M[r][k] / d;
        for (int cc = k; cc < 14; ++cc) M[r][cc] -= f * M[k][cc];
      }
    }
    float thx[12], thy[12];
    for (int k = 11; k >= 0; --k) {
      float sx = M[k][12], sy = M[k][13];
      for (int cc = k + 1; cc < 12; ++cc) {
        sx -= M[k][cc] * thx[cc];
        sy -= M[k][cc] * thy[cc];
      }
      thx[k] = sx / M[k][k];
      thy[k] = sy / M[k][k];
    }
    float swx = 0.f, swy = 0.f;
    for (int p = 1; p < 9; ++p) {
      sWx[p] = thx[p]; sWy[p] = thy[p];
      swx += thx[p];   swy += thy[p];
    }
    sWx[0] = -swx; sWy[0] = -swy;
    for (int p = 0; p < 3; ++p) { sAx[p] = thx[9 + p]; sAy[p] = thy[9 + p]; }
    for (int p = 0; p < 9; ++p) { sDstX[p] = dx[p]; sDstY[p] = dy[p]; }
  }
  __syncthreads();
  for (int p = threadIdx.x; p < 256; p += 64) {
    const int pi = p >> 4, pj = p & 15;
    const float x = pj * (1.f / 15.f), y = pi * (1.f / 15.f);
    float zx = sAx[0] + x * sAx[1] + y * sAx[2];
    float zy = sAy[0] + x * sAy[1] + y * sAy[2];
#pragma unroll
    for (int c = 0; c < 9; ++c) {
      const float ddx = x - sDstX[c], ddy = y - sDstY[c];
      const float r = sqrtf(ddx * ddx + ddy * ddy + 1e-12f);
      const float u = tps_u(r);
      zx += u * sWx[c];
      zy += u * sWy[c];
    }
    axb[b * 256 + p] = (x + zx) * 15.f;
    ayb[b * 256 + p] = (y + zy) * 15.f;
  }
}

// ---------------------------------------------------------------- masked sum
__global__ __launch_bounds__(256) void masksum_k(const float* __restrict__ corr,
                                                 const float* __restrict__ axb,
                                                 const float* __restrict__ ayb,
                                                 float* __restrict__ out) {
  const int b = blockIdx.x;
  const int pB = threadIdx.x;
  const float ax = axb[b * 256 + pB];
  const float ay = ayb[b * 256 + pB];
  const float* __restrict__ cb = corr + (size_t)b * 65536;
  float s = 0.f;
  for (int i = 0; i < 16; ++i) {
    if (fabsf((float)i - ay) <= 1.0f) {
      const float* __restrict__ ci = cb + (size_t)i * 16 * 256 + pB;
      for (int j = 0; j < 16; ++j) {
        if (fabsf((float)j - ax) <= 1.0f) s += ci[(size_t)j * 256];
      }
    }
  }
  __shared__ float sm[256];
  sm[pB] = s;
  __syncthreads();
  for (int off = 128; off; off >>= 1) {
    if (pB < off) sm[pB] += sm[pB + off];
    __syncthreads();
  }
  if (pB == 0) out[b] = sm[0];
}

// ---------------------------------------------------------------- launch
extern "C" void kernel_launch(void* const* d_in, const int* in_sizes, int n_in,
                              void* d_out, int out_size, void* d_ws, size_t ws_size,
                              hipStream_t stream) {
  const float* imgA = (const float*)d_in[0];
  const float* imgB = (const float*)d_in[1];
  const float* W1 = (const float*)d_in[2];
  const float* W2 = (const float*)d_in[3];
  const float* W3 = (const float*)d_in[4];
  const float* W4 = (const float*)d_in[5];
  const float* Wr1 = (const float*)d_in[6];
  const float* Wr2 = (const float*)d_in[7];
  const float* Wd = (const float*)d_in[8];
  const float* bd = (const float*)d_in[9];

  float* ws = (float*)d_ws;
  unsigned short* WT2 = (unsigned short*)(ws + 0);
  unsigned short* WT3 = (unsigned short*)(ws + 36864);
  unsigned short* WT4 = (unsigned short*)(ws + 184320);
  unsigned short* WTr1 = (unsigned short*)(ws + 774144);
  unsigned short* WTr2 = (unsigned short*)(ws + 2379776);
  unsigned short* FEATs = (unsigned short*)(ws + 2584576);
  unsigned short* S2 = (unsigned short*)(ws + 6778880);
  unsigned short* S1 = (unsigned short*)(ws + 15167488);
  unsigned short* S3 = (unsigned short*)(ws + 15167488);   // overlays S1
  unsigned short* FEATsp = (unsigned short*)(ws + 6778880); // overlays S2
  float* CORRf = ws + 15167488;                             // overlays S3
  unsigned short* CORRh = (unsigned short*)(ws + 17264640);
  float* R1p = ws + 19361792;
  unsigned short* R1h = (unsigned short*)(ws + 22228992);
  float* R2p = ws + 22638592;
  float* R2f = ws + 24481792;
  float* GEOb = ws + 24555520;
  float* AXb = ws + 24556096;
  float* AYb = ws + 24564288;

  // weight prep
  wt_single<<<288, 256, 0, stream>>>(W2, WT2, 576, 128);
  wt_single<<<1152, 256, 0, stream>>>(W3, WT3, 1152, 256);
  wt_single<<<4608, 256, 0, stream>>>(W4, WT4, 2304, 512);
  wt_split<<<6272, 256, 0, stream>>>(Wr1, WTr1, 12544, 128);
  wt_split<<<800, 256, 0, stream>>>(Wr2, WTr2, 3200, 64);

  for (int img = 0; img < 2; ++img) {
    const float* src = img ? imgB : imgA;
    for (int half = 0; half < 2; ++half) {
      conv1_k<<<dim3(32, 128, 16), 64, 0, stream>>>(src + (size_t)half * 3145728,
                                                    W1, S1);
      // conv2: M = 16*64*64 = 65536 -> 512x1 blocks of 128x128
      tile_conv<128, 128, 64, 128, 3, 3, 2>
          <<<dim3(512, 1), 256, 0, stream>>>(S1, WT2, S2 + (size_t)half * 8388608,
                                             128, 128, 64, 64);
    }
    // conv3: M = 32*32*32 = 32768 -> 256x2 blocks
    tile_conv<128, 128, 128, 256, 3, 3, 2>
        <<<dim3(256, 2), 256, 0, stream>>>(S2, WT3, S3, 64, 64, 32, 32);
    // conv4: M = 32*16*16 = 8192 -> 128x4 blocks of 64x128
    tile_conv<64, 128, 256, 512, 3, 3, 2>
        <<<dim3(128, 4), 256, 0, stream>>>(S3, WT4, FEATs + (size_t)img * 4194304,
                                           32, 32, 16, 16);
  }

  // l2norm: FEATs (single) -> FEATsp (split, lo at +8388608 el)
  l2norm_k<<<16384, 64, 0, stream>>>(FEATs, FEATsp, 8388608);
  // corr: split GEMM, A = img0 features, B = img1 features (batched rows)
  gemm_conv<1, 4, 512, 256, 1, 1, 1, 0, 0, 0, 1, 1, 1, 1>
      <<<dim3(128, 4, 1), 256, 0, stream>>>(FEATsp, FEATsp + 4194304, CORRh,
                                            CORRf, 16, 16, 16, 16,
                                            8388608, 8388608, 2097152);
  // conv_r1: split, split-K 7
  gemm_conv<2, 2, 256, 128, 7, 7, 1, 0, 1, 0, 0, 0, 7, 1>
      <<<dim3(25, 4, 7), 256, 0, stream>>>(CORRh, WTr1, nullptr, R1p,
                                           16, 16, 10, 10,
                                           2097152, 1605632, 0);
  sum_relu_h<<<1600, 256, 0, stream>>>(R1p, R1h, 409600, 7, 409600);
  // conv_r2: split, split-K 25
  gemm_conv<1, 4, 128, 64, 5, 5, 1, 0, 1, 0, 0, 0, 25, 1>
      <<<dim3(18, 1, 25), 256, 0, stream>>>(R1h, WTr2, nullptr, R2p,
                                            10, 10, 6, 6,
                                            409600, 204800, 0);
  sum_relu_f<<<288, 256, 0, stream>>>(R2p, R2f, 73728, 25);
  dense_k<<<dim3(18, 32), 64, 0, stream>>>(R2f, Wd, bd, GEOb);
  tps_k<<<32, 64, 0, stream>>>(GEOb, AXb, AYb);
  masksum_k<<<32, 256, 0, stream>>>(CORRf, AXb, AYb, (float*)d_out);
}

// Round 7
// 603.679 us; speedup vs baseline: 18.1130x; 1.2511x over previous
//
#include <hip/hip_runtime.h>
#include <math.h>

// ---------------------------------------------------------------------------
// Round 7: generalized LDS-tiled MFMA (split/split-K/batched-B/fp32-out).
//   conv2/3/4: tile_conv single fp16 (round-6 structure, full-image grids)
//   corr:      tile_conv SPLIT fp16 (hi+lo, 3xMFMA) -> CORRf fp32 + CORRh hi
//   conv_r1:   tile_conv single fp16, split-K 7 (was direct split: 155us,
//              176MB fetch, MfmaUtil 7.6%)
//   conv_r2:   direct gemm_conv single fp16, split-K 25
//   conv1 fp32->fp16 full-image; dense/tps/masksum fp32.
//
// Workspace (float units), peak 124.2 MB (<127.8 MB proven round 5):
//   WT2@0(36864) WT3@36864(147456) WT4@184320(589824)
//   WTr1@774144(802816,single) WTr2@1576960(102400,single)
//   FEATs @1679360 (4194304)   single fp16, 2 img x 8192 x 512
//   S2    @5873664 (8388608)   full img 32x64x64x128 fp16
//   S1    @14262272 (16777216) full img 32x128x128x64 fp16
//   S3    overlays S1 @14262272 (4194304)
//   post-chain: FEATsp @5873664 (8388608, hi+lo; overlays S2)
//     CORRf@14262272(2097152) CORRh@16359424(1048576, single)
//     R1p@17408000(7x409600) R1h@20275200(204800, single)
//     R2p@20480000(25x73728) R2f@22323200(73728)
//     GEO@22396928 AX@22397504 AY@22405696 -> end 22413888
// ---------------------------------------------------------------------------

typedef __attribute__((ext_vector_type(8))) _Float16 f16x8;
typedef __attribute__((ext_vector_type(4))) float f32x4;

__device__ __forceinline__ unsigned short f2h(float f) {
  return __builtin_bit_cast(unsigned short, (_Float16)f);
}
__device__ __forceinline__ float h2f(unsigned short u) {
  return (float)__builtin_bit_cast(_Float16, u);
}

// ---------------------------------------------------------------- weight prep
__global__ __launch_bounds__(256) void wt_single(const float* __restrict__ w,
                                                 unsigned short* __restrict__ wt,
                                                 int K, int C) {
  const int idx = blockIdx.x * 256 + threadIdx.x;
  if (idx < K * C) {
    const int k = idx / C, o = idx % C;
    wt[(size_t)o * K + k] = f2h(w[idx]);
  }
}

// ---------------------------------------------------------------- conv1
__global__ __launch_bounds__(64) void conv1_k(const float* __restrict__ in,
                                              const float* __restrict__ w,
                                              unsigned short* __restrict__ out) {
  const int o = threadIdx.x;
  const int j0 = blockIdx.x * 4;
  const int i = blockIdx.y;
  const int b = blockIdx.z;
  const float* __restrict__ inb = in + (size_t)b * 256 * 256 * 3;
  float acc[4] = {0.f, 0.f, 0.f, 0.f};
  const bool full = (2 * j0 + 8) < 256;
#pragma unroll
  for (int di = 0; di < 3; ++di) {
    const int y = 2 * i + di;
    if (y < 256) {
      const float* __restrict__ row = inb + ((size_t)y * 256 + 2 * j0) * 3;
      float xf[28];
      if (full) {
#pragma unroll
        for (int q = 0; q < 14; ++q) {
          const float2 v = ((const float2*)row)[q];
          xf[2 * q] = v.x; xf[2 * q + 1] = v.y;
        }
      } else {
#pragma unroll
        for (int q = 0; q < 12; ++q) {
          const float2 v = ((const float2*)row)[q];
          xf[2 * q] = v.x; xf[2 * q + 1] = v.y;
        }
        xf[24] = xf[25] = xf[26] = xf[27] = 0.f;
      }
#pragma unroll
      for (int c = 0; c < 3; ++c)
#pragma unroll
        for (int dj = 0; dj < 3; ++dj) {
          const float wv = w[(size_t)(((di * 3 + dj) * 3) + c) * 64 + o];
#pragma unroll
          for (int t = 0; t < 4; ++t) acc[t] += xf[(2 * t + dj) * 3 + c] * wv;
        }
    }
  }
#pragma unroll
  for (int t = 0; t < 4; ++t)
    out[(((size_t)b * 128 + i) * 128 + j0 + t) * 64 + o] = f2h(fmaxf(acc[t], 0.f));
}

// ---------------------------------------------------------------- tile conv
// LDS-tiled implicit-GEMM: out[m][n] = sum_k A[m][k]*Wt[n][k].
// SPLIT: A/B have hi+lo planes (aLo/bLo el offsets), 3 MFMAs per pair.
// SK>1: split-K over taps, fp32 partial slices to outf.
// BATB: B rows batched by A's batch index (corr).
// OUTF32: write fp32 to outf AND single fp16 hi to outh.
template <int BM, int BN, int CIN, int COUT, int KH, int KW, int STRIDE,
          int SAMEPAD, int SPLIT, int SK, int BATB, int OUTF32, int RELU>
__global__ __launch_bounds__(256) void tile_conv(
    const unsigned short* __restrict__ in, const unsigned short* __restrict__ wt,
    unsigned short* __restrict__ outh, float* __restrict__ outf,
    int Hin, int Win, int Hout, int Wout, int aLo, int bLo) {
  constexpr int LDA = 72;
  constexpr int CPT = CIN / 64;
  constexpr int LA = BM / 32;
  constexpr int LB = BN / 32;
  constexpr int KTOT = KH * KW * CIN;
  constexpr int MT = BM / 32;
  constexpr int NT = BN / 32;
  __shared__ _Float16 As[(1 + SPLIT) * BM * LDA];
  __shared__ _Float16 Bs[(1 + SPLIT) * BN * LDA];

  const int t = threadIdx.x;
  const int lane = t & 63, wid = t >> 6;
  const int lrow = lane & 15, quad = lane >> 4;
  const int m0 = blockIdx.x * BM;
  const int n0 = blockIdx.y * BN;

  int pixB[LA], iS[LA], jS[LA], lofA[LA];
#pragma unroll
  for (int i = 0; i < LA; ++i) {
    const int u = t + 256 * i;
    const int r = u >> 3, sl = u & 7;
    const int m = m0 + r;
    const int j = m % Wout;
    const int t2 = m / Wout;
    const int ii = t2 % Hout;
    const int b = t2 / Hout;
    iS[i] = ii * STRIDE;
    jS[i] = j * STRIDE;
    pixB[i] = ((b * Hin + iS[i]) * Win + jS[i]) * CIN + sl * 8;
    lofA[i] = r * LDA + sl * 8;
  }
  const unsigned short* wb = wt;
  if (BATB) wb += (size_t)(m0 / (Hout * Wout)) * COUT * KTOT;
  int bofB[LB], lofB[LB];
#pragma unroll
  for (int i = 0; i < LB; ++i) {
    const int u = t + 256 * i;
    const int r = u >> 3, sl = u & 7;
    bofB[i] = (n0 + r) * KTOT + sl * 8;
    lofB[i] = r * LDA + sl * 8;
  }

  const f16x8 zh = {0, 0, 0, 0, 0, 0, 0, 0};
  f32x4 acc[MT][NT];
#pragma unroll
  for (int mi = 0; mi < MT; ++mi)
#pragma unroll
    for (int ni = 0; ni < NT; ++ni) acc[mi][ni] = {0.f, 0.f, 0.f, 0.f};

  const int mB = (wid >> 1) * (BM / 2);
  const int nB = (wid & 1) * (BN / 2);

  int tap_lo = 0, tap_hi = KH * KW;
  if (SK > 1) {
    tap_lo = (int)blockIdx.z * KH * KW / SK;
    tap_hi = ((int)blockIdx.z + 1) * KH * KW / SK;
  }
  for (int ch = tap_lo * CPT; ch < tap_hi * CPT; ++ch) {
    const int tap = ch / CPT;
    const int c0 = (ch % CPT) * 64;
    const int di = tap / KW, dj = tap % KW;
    const int toff = (di * Win + dj) * CIN + c0;
    const int woff = tap * CIN + c0;
    f16x8 va[LA], vb[LB], va2[LA], vb2[LB];
#pragma unroll
    for (int i = 0; i < LA; ++i) {
      const bool ok = !SAMEPAD || ((iS[i] + di < Hin) && (jS[i] + dj < Win));
      va[i] = ok ? *(const f16x8*)(in + pixB[i] + toff) : zh;
      if (SPLIT) va2[i] = ok ? *(const f16x8*)(in + pixB[i] + toff + aLo) : zh;
    }
#pragma unroll
    for (int i = 0; i < LB; ++i) {
      vb[i] = *(const f16x8*)(wb + bofB[i] + woff);
      if (SPLIT) vb2[i] = *(const f16x8*)(wb + bofB[i] + woff + bLo);
    }
    __syncthreads();
#pragma unroll
    for (int i = 0; i < LA; ++i) {
      *(f16x8*)&As[lofA[i]] = va[i];
      if (SPLIT) *(f16x8*)&As[BM * LDA + lofA[i]] = va2[i];
    }
#pragma unroll
    for (int i = 0; i < LB; ++i) {
      *(f16x8*)&Bs[lofB[i]] = vb[i];
      if (SPLIT) *(f16x8*)&Bs[BN * LDA + lofB[i]] = vb2[i];
    }
    __syncthreads();
#pragma unroll
    for (int ks = 0; ks < 2; ++ks) {
      f16x8 af[MT], bf[NT], al[MT], bl[NT];
#pragma unroll
      for (int mi = 0; mi < MT; ++mi) {
        const int off = (mB + mi * 16 + lrow) * LDA + ks * 32 + quad * 8;
        af[mi] = *(const f16x8*)&As[off];
        if (SPLIT) al[mi] = *(const f16x8*)&As[BM * LDA + off];
      }
#pragma unroll
      for (int ni = 0; ni < NT; ++ni) {
        const int off = (nB + ni * 16 + lrow) * LDA + ks * 32 + quad * 8;
        bf[ni] = *(const f16x8*)&Bs[off];
        if (SPLIT) bl[ni] = *(const f16x8*)&Bs[BN * LDA + off];
      }
#pragma unroll
      for (int mi = 0; mi < MT; ++mi)
#pragma unroll
        for (int ni = 0; ni < NT; ++ni) {
          if (SPLIT) {
            acc[mi][ni] = __builtin_amdgcn_mfma_f32_16x16x32_f16(af[mi], bl[ni],
                                                                 acc[mi][ni], 0, 0, 0);
            acc[mi][ni] = __builtin_amdgcn_mfma_f32_16x16x32_f16(al[mi], bf[ni],
                                                                 acc[mi][ni], 0, 0, 0);
          }
          acc[mi][ni] = __builtin_amdgcn_mfma_f32_16x16x32_f16(af[mi], bf[ni],
                                                               acc[mi][ni], 0, 0, 0);
        }
    }
  }
  const size_t slice =
      (SK > 1) ? (size_t)blockIdx.z * ((size_t)gridDim.x * BM * COUT) : 0;
#pragma unroll
  for (int mi = 0; mi < MT; ++mi)
#pragma unroll
    for (int ni = 0; ni < NT; ++ni)
#pragma unroll
      for (int r = 0; r < 4; ++r) {
        const int row = m0 + mB + mi * 16 + quad * 4 + r;
        const int col = n0 + nB + ni * 16 + lrow;
        const size_t idx = (size_t)row * COUT + col;
        float v = acc[mi][ni][r];
        if (SK > 1) {
          outf[slice + idx] = v;
        } else if (OUTF32) {
          outf[idx] = v;
          outh[idx] = f2h(v);
        } else {
          if (RELU) v = fmaxf(v, 0.f);
          outh[idx] = f2h(v);
        }
      }
}

// ---------------------------------------------------------------- direct MFMA
// kept for conv_r2 (tiny), single plane.
template <int MT, int NT, int CIN, int COUT, int KH, int KW, int SK>
__global__ __launch_bounds__(256) void gemm_conv(
    const unsigned short* __restrict__ in, const unsigned short* __restrict__ wt,
    float* __restrict__ outf, int Hin, int Win, int Hout, int Wout) {
  const int KTOT = KH * KW * CIN;
  const int lane = threadIdx.x & 63;
  const int wid = threadIdx.x >> 6;
  const int lrow = lane & 15;
  const int quad = lane >> 4;
  const int m0 = (blockIdx.x * 4 + wid) * (16 * MT);
  const int n0 = blockIdx.y * (16 * NT);

  int pix[MT];
#pragma unroll
  for (int mi = 0; mi < MT; ++mi) {
    const int m = m0 + mi * 16 + lrow;
    const int j = m % Wout;
    const int t = m / Wout;
    const int i = t % Hout;
    const int b = t / Hout;
    pix[mi] = (b * Hin + i) * Win + j;
  }
  const unsigned short* brow[NT];
#pragma unroll
  for (int ni = 0; ni < NT; ++ni)
    brow[ni] = wt + (size_t)(n0 + ni * 16 + lrow) * KTOT + quad * 8;

  f32x4 acc[MT][NT];
#pragma unroll
  for (int mi = 0; mi < MT; ++mi)
#pragma unroll
    for (int ni = 0; ni < NT; ++ni) acc[mi][ni] = {0.f, 0.f, 0.f, 0.f};

  const int tap_lo = (int)blockIdx.z * KH * KW / SK;
  const int tap_hi = ((int)blockIdx.z + 1) * KH * KW / SK;
  for (int tap = tap_lo; tap < tap_hi; ++tap) {
    const int di = tap / KW, dj = tap % KW;
    const unsigned short* ap[MT];
#pragma unroll
    for (int mi = 0; mi < MT; ++mi)
      ap[mi] = in + ((size_t)pix[mi] + di * Win + dj) * CIN + quad * 8;
    const int ko = tap * CIN;
#pragma unroll
    for (int c0 = 0; c0 < CIN; c0 += 32) {
      f16x8 ah[MT], bh[NT];
#pragma unroll
      for (int mi = 0; mi < MT; ++mi) ah[mi] = *(const f16x8*)(ap[mi] + c0);
#pragma unroll
      for (int ni = 0; ni < NT; ++ni) bh[ni] = *(const f16x8*)(brow[ni] + ko + c0);
#pragma unroll
      for (int mi = 0; mi < MT; ++mi)
#pragma unroll
        for (int ni = 0; ni < NT; ++ni)
          acc[mi][ni] = __builtin_amdgcn_mfma_f32_16x16x32_f16(ah[mi], bh[ni],
                                                               acc[mi][ni], 0, 0, 0);
    }
  }
  const size_t slice = (size_t)blockIdx.z * ((size_t)gridDim.x * 64 * MT * COUT);
#pragma unroll
  for (int mi = 0; mi < MT; ++mi)
#pragma unroll
    for (int ni = 0; ni < NT; ++ni)
#pragma unroll
      for (int r = 0; r < 4; ++r) {
        const int row = m0 + mi * 16 + quad * 4 + r;
        const int col = n0 + ni * 16 + lrow;
        outf[slice + (size_t)row * COUT + col] = acc[mi][ni][r];
      }
}

// ---------------------------------------------------------------- split-K epi
__global__ __launch_bounds__(256) void sum_relu_s(const float* __restrict__ p,
                                                  unsigned short* __restrict__ o,
                                                  int n, int parts) {
  const int idx = blockIdx.x * 256 + threadIdx.x;
  if (idx < n) {
    float v = 0.f;
    for (int s = 0; s < parts; ++s) v += p[(size_t)s * n + idx];
    o[idx] = f2h(fmaxf(v, 0.f));
  }
}
__global__ __launch_bounds__(256) void sum_relu_f(const float* __restrict__ p,
                                                  float* __restrict__ o,
                                                  int n, int parts) {
  const int idx = blockIdx.x * 256 + threadIdx.x;
  if (idx < n) {
    float v = 0.f;
    for (int s = 0; s < parts; ++s) v += p[(size_t)s * n + idx];
    o[idx] = fmaxf(v, 0.f);
  }
}

// ---------------------------------------------------------------- l2 normalize
// in: single fp16; out: split pair (hi @y, lo @y+loOff).
__global__ __launch_bounds__(64) void l2norm_k(const unsigned short* __restrict__ x,
                                               unsigned short* __restrict__ y,
                                               int loOff) {
  const int lane = threadIdx.x;
  const f16x8 v = *(const f16x8*)(x + (size_t)blockIdx.x * 512 + lane * 8);
  float f[8];
  float s = 0.f;
#pragma unroll
  for (int k = 0; k < 8; ++k) {
    f[k] = (float)v[k];
    s += f[k] * f[k];
  }
#pragma unroll
  for (int off = 32; off; off >>= 1) s += __shfl_xor(s, off, 64);
  const float inv = 1.f / (sqrtf(s) + 1e-6f);
  f16x8 vh, vl;
#pragma unroll
  for (int k = 0; k < 8; ++k) {
    const float nv = f[k] * inv;
    const _Float16 hi = (_Float16)nv;
    vh[k] = hi;
    vl[k] = (_Float16)(nv - (float)hi);
  }
  unsigned short* ph = y + (size_t)blockIdx.x * 512 + lane * 8;
  *(f16x8*)ph = vh;
  *(f16x8*)(ph + (size_t)loOff) = vl;
}

// ---------------------------------------------------------------- dense
__global__ __launch_bounds__(64) void dense_k(const float* __restrict__ r2,
                                              const float* __restrict__ wd,
                                              const float* __restrict__ bd,
                                              float* __restrict__ geo) {
  const int o = blockIdx.x;
  const int b = blockIdx.y;
  const int lane = threadIdx.x;
  const float* __restrict__ rb = r2 + (size_t)b * 2304;
  float s = 0.f;
  for (int k = lane; k < 2304; k += 64) s += rb[k] * wd[(size_t)k * 18 + o];
#pragma unroll
  for (int off = 32; off; off >>= 1) s += __shfl_xor(s, off, 64);
  if (lane == 0) geo[b * 18 + o] = s + bd[o];
}

// ---------------------------------------------------------------- TPS
__device__ __forceinline__ float tps_u(float r) { return r * r * logf(r + 1e-6f); }

__global__ __launch_bounds__(64) void tps_k(const float* __restrict__ geo,
                                            float* __restrict__ axb,
                                            float* __restrict__ ayb) {
  const int b = blockIdx.x;
  __shared__ float sDstX[9], sDstY[9];
  __shared__ float sWx[9], sWy[9];
  __shared__ float sAx[3], sAy[3];
  if (threadIdx.x == 0) {
    const float srcx[9] = {0.f, 0.5f, 1.f, 0.f, 0.5f, 1.f, 0.f, 5.f, 1.f};
    const float srcy[9] = {0.f, 0.f, 0.f, 0.5f, 0.5f, 0.5f, 1.f, 1.f, 1.f};
    float dx[9], dy[9];
    float M[12][14];
    for (int r = 0; r < 12; ++r)
      for (int cc = 0; cc < 14; ++cc) M[r][cc] = 0.f;
    for (int p = 0; p < 9; ++p) {
      const float mx = geo[b * 18 + 2 * p], my = geo[b * 18 + 2 * p + 1];
      dx[p] = srcx[p] + mx;
      dy[p] = srcy[p] + my;
      M[p][12] = -mx;
      M[p][13] = -my;
    }
    for (int p = 0; p < 9; ++p) {
      for (int q = 0; q < 9; ++q) {
        const float ddx = dx[p] - dx[q], ddy = dy[p] - dy[q];
        const float r = sqrtf(ddx * ddx + ddy * ddy + 1e-12f);
        M[p][q] = tps_u(r);
      }
      M[p][9] = 1.f;  M[p][10] = dx[p]; M[p][11] = dy[p];
      M[9][p] = 1.f;  M[10][p] = dx[p]; M[11][p] = dy[p];
    }
    for (int k = 0; k < 12; ++k) {
      int piv = k;
      float best = fabsf(M[k][k]);
      for (int r = k + 1; r < 12; ++r) {
        const float v = fabsf(M[r][k]);
        if (v > best) { best = v; piv = r; }
      }
      if (piv != k)
        for (int cc = k; cc < 14; ++cc) {
          const float tmp = M[k][cc]; M[k][cc] = M[piv][cc]; M[piv][cc] = tmp;
        }
      const float d = M[k][k];
      for (int r = k + 1; r < 12; ++r) {
        const float f = M[r][k] / d;
        for (int cc = k; cc < 14; ++cc) M[r][cc] -= f * M[k][cc];
      }
    }
    float thx[12], thy[12];
    for (int k = 11; k >= 0; --k) {
      float sx = M[k][12], sy = M[k][13];
      for (int cc = k + 1; cc < 12; ++cc) {
        sx -= M[k][cc] * thx[cc];
        sy -= M[k][cc] * thy[cc];
      }
      thx[k] = sx / M[k][k];
      thy[k] = sy / M[k][k];
    }
    float swx = 0.f, swy = 0.f;
    for (int p = 1; p < 9; ++p) {
      sWx[p] = thx[p]; sWy[p] = thy[p];
      swx += thx[p];   swy += thy[p];
    }
    sWx[0] = -swx; sWy[0] = -swy;
    for (int p = 0; p < 3; ++p) { sAx[p] = thx[9 + p]; sAy[p] = thy[9 + p]; }
    for (int p = 0; p < 9; ++p) { sDstX[p] = dx[p]; sDstY[p] = dy[p]; }
  }
  __syncthreads();
  for (int p = threadIdx.x; p < 256; p += 64) {
    const int pi = p >> 4, pj = p & 15;
    const float x = pj * (1.f / 15.f), y = pi * (1.f / 15.f);
    float zx = sAx[0] + x * sAx[1] + y * sAx[2];
    float zy = sAy[0] + x * sAy[1] + y * sAy[2];
#pragma unroll
    for (int c = 0; c < 9; ++c) {
      const float ddx = x - sDstX[c], ddy = y - sDstY[c];
      const float r = sqrtf(ddx * ddx + ddy * ddy + 1e-12f);
      const float u = tps_u(r);
      zx += u * sWx[c];
      zy += u * sWy[c];
    }
    axb[b * 256 + p] = (x + zx) * 15.f;
    ayb[b * 256 + p] = (y + zy) * 15.f;
  }
}

// ---------------------------------------------------------------- masked sum
__global__ __launch_bounds__(256) void masksum_k(const float* __restrict__ corr,
                                                 const float* __restrict__ axb,
                                                 const float* __restrict__ ayb,
                                                 float* __restrict__ out) {
  const int b = blockIdx.x;
  const int pB = threadIdx.x;
  const float ax = axb[b * 256 + pB];
  const float ay = ayb[b * 256 + pB];
  const float* __restrict__ cb = corr + (size_t)b * 65536;
  float s = 0.f;
  for (int i = 0; i < 16; ++i) {
    if (fabsf((float)i - ay) <= 1.0f) {
      const float* __restrict__ ci = cb + (size_t)i * 16 * 256 + pB;
      for (int j = 0; j < 16; ++j) {
        if (fabsf((float)j - ax) <= 1.0f) s += ci[(size_t)j * 256];
      }
    }
  }
  __shared__ float sm[256];
  sm[pB] = s;
  __syncthreads();
  for (int off = 128; off; off >>= 1) {
    if (pB < off) sm[pB] += sm[pB + off];
    __syncthreads();
  }
  if (pB == 0) out[b] = sm[0];
}

// ---------------------------------------------------------------- launch
extern "C" void kernel_launch(void* const* d_in, const int* in_sizes, int n_in,
                              void* d_out, int out_size, void* d_ws, size_t ws_size,
                              hipStream_t stream) {
  const float* imgA = (const float*)d_in[0];
  const float* imgB = (const float*)d_in[1];
  const float* W1 = (const float*)d_in[2];
  const float* W2 = (const float*)d_in[3];
  const float* W3 = (const float*)d_in[4];
  const float* W4 = (const float*)d_in[5];
  const float* Wr1 = (const float*)d_in[6];
  const float* Wr2 = (const float*)d_in[7];
  const float* Wd = (const float*)d_in[8];
  const float* bd = (const float*)d_in[9];

  float* ws = (float*)d_ws;
  unsigned short* WT2 = (unsigned short*)(ws + 0);
  unsigned short* WT3 = (unsigned short*)(ws + 36864);
  unsigned short* WT4 = (unsigned short*)(ws + 184320);
  unsigned short* WTr1 = (unsigned short*)(ws + 774144);
  unsigned short* WTr2 = (unsigned short*)(ws + 1576960);
  unsigned short* FEATs = (unsigned short*)(ws + 1679360);
  unsigned short* S2 = (unsigned short*)(ws + 5873664);
  unsigned short* S1 = (unsigned short*)(ws + 14262272);
  unsigned short* S3 = (unsigned short*)(ws + 14262272);    // overlays S1
  unsigned short* FEATsp = (unsigned short*)(ws + 5873664); // overlays S2
  float* CORRf = ws + 14262272;                             // overlays S1/S3
  unsigned short* CORRh = (unsigned short*)(ws + 16359424);
  float* R1p = ws + 17408000;
  unsigned short* R1h = (unsigned short*)(ws + 20275200);
  float* R2p = ws + 20480000;
  float* R2f = ws + 22323200;
  float* GEOb = ws + 22396928;
  float* AXb = ws + 22397504;
  float* AYb = ws + 22405696;

  // weight prep (all single-plane except none)
  wt_single<<<288, 256, 0, stream>>>(W2, WT2, 576, 128);
  wt_single<<<1152, 256, 0, stream>>>(W3, WT3, 1152, 256);
  wt_single<<<4608, 256, 0, stream>>>(W4, WT4, 2304, 512);
  wt_single<<<6272, 256, 0, stream>>>(Wr1, WTr1, 12544, 128);
  wt_single<<<800, 256, 0, stream>>>(Wr2, WTr2, 3200, 64);

  for (int img = 0; img < 2; ++img) {
    const float* src = img ? imgB : imgA;
    conv1_k<<<dim3(32, 128, 32), 64, 0, stream>>>(src, W1, S1);
    // conv2: M = 32*4096 = 131072 -> 1024 blocks of 128x128
    tile_conv<128, 128, 64, 128, 3, 3, 2, 1, 0, 1, 0, 0, 1>
        <<<dim3(1024, 1), 256, 0, stream>>>(S1, WT2, S2, nullptr,
                                            128, 128, 64, 64, 0, 0);
    // conv3: M = 32768 -> 256x2
    tile_conv<128, 128, 128, 256, 3, 3, 2, 1, 0, 1, 0, 0, 1>
        <<<dim3(256, 2), 256, 0, stream>>>(S2, WT3, S3, nullptr,
                                           64, 64, 32, 32, 0, 0);
    // conv4: M = 8192 -> 128x4 of 64x128
    tile_conv<64, 128, 256, 512, 3, 3, 2, 1, 0, 1, 0, 0, 1>
        <<<dim3(128, 4), 256, 0, stream>>>(S3, WT4, FEATs + (size_t)img * 4194304,
                                           nullptr, 32, 32, 16, 16, 0, 0);
  }

  // l2norm: FEATs (single) -> FEATsp (split pair, lo at +8388608 el)
  l2norm_k<<<16384, 64, 0, stream>>>(FEATs, FEATsp, 8388608);
  // corr: tiled split GEMM (batched B), fp32 out + single fp16 hi out
  tile_conv<64, 64, 512, 256, 1, 1, 1, 0, 1, 1, 1, 1, 0>
      <<<dim3(128, 4), 256, 0, stream>>>(FEATsp, FEATsp + 4194304, CORRh, CORRf,
                                         16, 16, 16, 16, 8388608, 8388608);
  // conv_r1: tiled single fp16, split-K 7 -> fp32 partials
  tile_conv<64, 128, 256, 128, 7, 7, 1, 0, 0, 7, 0, 0, 0>
      <<<dim3(50, 1, 7), 256, 0, stream>>>(CORRh, WTr1, nullptr, R1p,
                                           16, 16, 10, 10, 0, 0);
  sum_relu_s<<<1600, 256, 0, stream>>>(R1p, R1h, 409600, 7);
  // conv_r2: direct single fp16, split-K 25
  gemm_conv<1, 4, 128, 64, 5, 5, 25>
      <<<dim3(18, 1, 25), 256, 0, stream>>>(R1h, WTr2, R2p, 10, 10, 6, 6);
  sum_relu_f<<<288, 256, 0, stream>>>(R2p, R2f, 73728, 25);
  dense_k<<<dim3(18, 32), 64, 0, stream>>>(R2f, Wd, bd, GEOb);
  tps_k<<<32, 64, 0, stream>>>(GEOb, AXb, AYb);
  masksum_k<<<32, 256, 0, stream>>>(CORRf, AXb, AYb, (float*)d_out);
}